// Round 8
// baseline (1487.902 us; speedup 1.0000x reference)
//
#include <hip/hip_runtime.h>
#include <math.h>

#define DEVI __device__ __forceinline__

typedef __attribute__((ext_vector_type(8))) short short8;
typedef __attribute__((ext_vector_type(4))) float f32x4;

DEVI float bf2f(short u){ unsigned v = ((unsigned)(unsigned short)u) << 16; return __builtin_bit_cast(float, v); }
DEVI short f2bs(float f){
  unsigned x = __builtin_bit_cast(unsigned, f);
  unsigned r = (x + 0x7fffu + ((x >> 16) & 1u)) >> 16;
  return (short)(unsigned short)r;
}
DEVI float clampf(float x, float lo, float hi){ return fminf(fmaxf(x, lo), hi); }
DEVI float n2nf(float x){
  if (x != x) return 0.f;
  if (x == INFINITY) return 1.f;
  if (x == -INFINITY) return -1.f;
  return x;
}
DEVI float sigmoidf(float x){ return 1.f/(1.f+expf(-x)); }
DEVI f32x4 mfma16(short8 a, short8 b, f32x4 c){ return __builtin_amdgcn_mfma_f32_16x16x32_bf16(a,b,c,0,0,0); }

DEVI float blkSum(float v, float* s4, int tid){
  #pragma unroll
  for (int o=32;o;o>>=1) v += __shfl_xor(v,o);
  __syncthreads();
  if ((tid&63)==0) s4[tid>>6] = v;
  __syncthreads();
  return s4[0]+s4[1]+s4[2]+s4[3];
}

// ---------------- utility kernels ----------------
__global__ void k_convert(const float* __restrict__ s, short* __restrict__ d, int n){
  int i = blockIdx.x*256 + threadIdx.x;
  if (i < n) d[i] = f2bs(s[i]);
}

__global__ void k_prep_gwp(const float* __restrict__ gw, const float* __restrict__ gb, short* __restrict__ gwp){
  int i = blockIdx.x*256 + threadIdx.x;   // 0..16383
  int d = i >> 6, c = i & 63;
  float v = (c < 39) ? gw[d*39 + c] : (c == 39 ? gb[d] : 0.f);
  gwp[i] = f2bs(v);
}

__global__ void k_init(const float* __restrict__ slots_p, const float* __restrict__ Sp0, const float* __restrict__ Ss0,
                       float* __restrict__ slots, float* __restrict__ sp, float* __restrict__ ssb){
  int bs = blockIdx.x, t = threadIdx.x, s = bs & 7;
  slots[bs*256+t] = slots_p[s*256+t];
  if (t < 3){ sp[bs*3+t] = Sp0[s*3+t]; ssb[bs*3+t] = Ss0[s*3+t]; }
}

__global__ __launch_bounds__(256) void k_ln768(const float* __restrict__ in, const float* __restrict__ g,
                                               const float* __restrict__ bt, short* __restrict__ out){
  int r = blockIdx.x, t = threadIdx.x;
  __shared__ float s4[4];
  const float* row = in + (size_t)r*768;
  float x0=row[t], x1=row[256+t], x2=row[512+t];
  float m = blkSum(x0+x1+x2, s4, t) * (1.f/768.f);
  float d0=x0-m, d1=x1-m, d2=x2-m;
  float var = blkSum(d0*d0+d1*d1+d2*d2, s4, t) * (1.f/768.f);
  float rstd = 1.f/sqrtf(var + 1e-5f);
  short* orow = out + (size_t)r*768;
  orow[t]     = f2bs(d0*rstd*g[t]     + bt[t]);
  orow[256+t] = f2bs(d1*rstd*g[256+t] + bt[256+t]);
  orow[512+t] = f2bs(d2*rstd*g[512+t] + bt[512+t]);
}

__global__ __launch_bounds__(256) void k_ln256(const float* __restrict__ in, const float* __restrict__ g,
                                               const float* __restrict__ bt, short* __restrict__ out){
  int r = blockIdx.x, t = threadIdx.x;
  __shared__ float s4[4];
  float x = in[(size_t)r*256 + t];
  float m = blkSum(x, s4, t) * (1.f/256.f);
  float d = x - m;
  float var = blkSum(d*d, s4, t) * (1.f/256.f);
  out[(size_t)r*256 + t] = f2bs(d*(1.f/sqrtf(var+1e-5f))*g[t] + bt[t]);
}

// ---------------- generic MFMA GEMM (runtime KT/flags) ----------------
// out[M x Ncols] = A[M x KT] @ W[Ncols x KT]^T (+bias)(+relu)
// flags: 1=bias, 2=relu, 4=bf16out
__global__ __launch_bounds__(256) void k_gemm(const short* __restrict__ A, const short* __restrict__ W,
                                              const float* __restrict__ bias, void* __restrict__ outp,
                                              int ldo, int KT, int flags){
  const int w = threadIdx.x>>6, l = threadIdx.x&63, l15 = l&15, l4 = l>>4;
  const int row0 = blockIdx.x*64 + w*16;
  const int col0 = blockIdx.y*128;
  f32x4 acc[8];
  #pragma unroll
  for (int i=0;i<8;i++) acc[i] = (f32x4)(0.f);
  const short* Ap  = A + (size_t)(row0+l15)*KT + l4*8;
  const short* Wp0 = W + (size_t)(col0+l15)*KT + l4*8;
  #pragma unroll 2
  for (int kk=0; kk<KT/32; ++kk){
    short8 af = *(const short8*)(Ap + kk*32);
    #pragma unroll
    for (int ci=0; ci<8; ++ci){
      short8 bfr = *(const short8*)(Wp0 + (size_t)ci*16*KT + kk*32);
      acc[ci] = mfma16(af, bfr, acc[ci]);
    }
  }
  #pragma unroll
  for (int ci=0; ci<8; ++ci){
    int col = col0 + ci*16 + l15;
    float bv = (flags&1) ? bias[col] : 0.f;
    #pragma unroll
    for (int j=0;j<4;j++){
      int row = row0 + l4*4 + j;
      float v = acc[ci][j] + bv;
      if (flags&2) v = fmaxf(v, 0.f);
      if (flags&4) ((short*)outp)[(size_t)row*ldo + col] = f2bs(v);
      else         ((float*)outp)[(size_t)row*ldo + col] = v;
    }
  }
}

// ---------------- per-iteration small kernel: sn=LN(slots); q=sn@Qw^T; qf2=q@f2w; qb=q.f2b ----------------
__global__ __launch_bounds__(256) void k_qprep(const float* __restrict__ slots,
    const float* __restrict__ ng, const float* __restrict__ nb,
    const float* __restrict__ Qw, const float* __restrict__ f2w, const float* __restrict__ f2b,
    float* __restrict__ qf2, float* __restrict__ qbv){
  int bs = blockIdx.x, t = threadIdx.x;
  __shared__ float sn[256], q[256], s4[4];
  float x = slots[bs*256+t];
  float m = blkSum(x, s4, t)*(1.f/256.f);
  float d = x - m;
  float var = blkSum(d*d, s4, t)*(1.f/256.f);
  sn[t] = d*(1.f/sqrtf(var+1e-5f))*ng[t] + nb[t];
  __syncthreads();
  {
    const float4* qr = (const float4*)(Qw + (size_t)t*256);
    float s = 0.f;
    for (int d4=0; d4<64; ++d4){
      float4 w4 = qr[d4];
      s += sn[d4*4+0]*w4.x + sn[d4*4+1]*w4.y + sn[d4*4+2]*w4.z + sn[d4*4+3]*w4.w;
    }
    q[t] = s;
  }
  __syncthreads();
  {
    float s = 0.f;
    for (int o=0;o<256;o++) s += q[o]*f2w[(size_t)o*256 + t];
    qf2[bs*256+t] = s;
  }
  float tot = blkSum(q[t]*f2b[t], s4, t);
  if (t==0) qbv[bs] = tot;
}

// ---------------- the big fused kernel ----------------
// grid (N/64, B*S), 256 threads. Per wave: 16 rows x 256 cols.
// per pass: gr = ff@gwp^T -> abuf(LDS) ; abuf += Kx|Vx (vectorized) ;
//           H=relu(abuf@f1w^T+f1b) ; pass0: dots=clip((H.qf2+qb)*SCALE) ; pass1: hv=H (staged via abuf, vector stores)
__global__ __launch_bounds__(256) void k_isa_a(
    const float* __restrict__ coords, const float* __restrict__ sp, const float* __restrict__ ssb,
    const short* __restrict__ gwp, const short* __restrict__ kx, const short* __restrict__ vx,
    const short* __restrict__ f1w, const float* __restrict__ f1b,
    const float* __restrict__ qf2, const float* __restrict__ qbv,
    float* __restrict__ dots, short* __restrict__ hv, int npass){
  __shared__ __align__(16) short ffs[64*64];
  __shared__ __align__(16) short abuf[64*256];
  __shared__ float sf1b[256];
  __shared__ float sqf2[256];
  __shared__ float smisc[8];
  const int tid = threadIdx.x;
  const int bs = blockIdx.y;
  const int b  = bs >> 3;
  const int n0 = blockIdx.x * 64;

  sf1b[tid] = f1b[tid];
  sqf2[tid] = qf2[bs*256 + tid];
  if (tid < 3){
    smisc[tid] = sp[bs*3+tid];
    float sv = ssb[bs*3+tid];
    float sa = clampf(sv, 0.3f, 5.f) + 0.1f;
    smisc[4+tid] = 1.f/(sa*5.f + 1e-4f);
  }
  if (tid == 7) smisc[7] = qbv[bs];
  __syncthreads();

  // fourier features into ffs (row n: [rel0..2, sin/cos interleaved (36), 1(bias), 0-pad -> 64])
  {
    const float FRQ[6] = {6.283185307179586f,12.566370614359172f,25.132741228718345f,
                          50.26548245743669f,100.53096491487338f,201.06192982974676f};
    int n  = tid >> 2;
    int cb = (tid & 3) * 16;
    float rel[3];
    #pragma unroll
    for (int i=0;i<3;i++){
      float c = coords[((size_t)(b*2048 + n0 + n))*3 + i];
      rel[i] = clampf((c - smisc[i]) * smisc[4+i], -3.f, 3.f);
    }
    #pragma unroll 1
    for (int cc=0; cc<16; ++cc){
      int c = cb + cc;
      float v;
      if (c < 3) v = rel[c];
      else if (c < 39){
        int q = c-3; int i = q/12; int j = (q%12)>>1;
        float ang = rel[i]*FRQ[j];
        v = (q & 1) ? cosf(ang) : sinf(ang);
      }
      else if (c == 39) v = 1.f;
      else v = 0.f;
      ffs[n*64 + (((c>>3)^(n&7))<<3) + (c&7)] = f2bs(v);
    }
  }
  __syncthreads();

  const int w = tid>>6, l = tid&63, l15 = l&15, l4 = l>>4;
  const int ar = w*16 + l15;           // A-row this lane reads (wave-private)
  f32x4 acc[16];

  #pragma unroll 1
  for (int pass = 0; pass < npass; ++pass){
    // ---- gr GEMM (K=64) ----
    #pragma unroll
    for (int ci=0;ci<16;ci++) acc[ci] = (f32x4)(0.f);
    #pragma unroll
    for (int kk=0;kk<2;kk++){
      short8 af = *(const short8*)&ffs[ar*64 + (((kk*4+l4) ^ (ar&7))<<3)];
      #pragma unroll
      for (int ci=0;ci<16;ci++){
        short8 bfr = *(const short8*)&gwp[(size_t)(ci*16+l15)*64 + kk*32 + l4*8];
        acc[ci] = mfma16(af, bfr, acc[ci]);
      }
    }
    // ---- write gr -> abuf (bf16, swizzled; wave-private rows) ----
    #pragma unroll
    for (int ci=0;ci<16;ci++){
      #pragma unroll
      for (int j=0;j<4;j++){
        int row = w*16 + l4*4 + j;
        int col = ci*16 + l15;
        abuf[row*256 + (((col>>3)^(row&7))<<3) + (col&7)] = f2bs(acc[ci][j]);
      }
    }
    __syncthreads();
    // ---- abuf += Kx|Vx  (vectorized short8 RMW; 8 groups/thread) ----
    {
      const short* srcb = pass ? vx : kx;
      #pragma unroll
      for (int i=0;i<8;i++){
        int gid = tid + i*256;          // 0..2047
        int row = gid>>5, cg = gid&31;  // 64 rows x 32 col-groups
        short8 sv = *(const short8*)(srcb + ((size_t)(b*2048 + n0 + row))*256 + cg*8);
        short* ap = &abuf[row*256 + ((cg^(row&7))<<3)];
        short8 av = *(const short8*)ap;
        short8 ov;
        #pragma unroll
        for (int e=0;e<8;e++) ov[e] = f2bs(bf2f(av[e]) + bf2f(sv[e]));
        *(short8*)ap = ov;
      }
    }
    __syncthreads();
    // ---- f1 GEMM (K=256) ----
    #pragma unroll
    for (int ci=0;ci<16;ci++) acc[ci] = (f32x4)(0.f);
    #pragma unroll 2
    for (int kk=0;kk<8;kk++){
      short8 af = *(const short8*)&abuf[ar*256 + (((kk*4+l4) ^ (ar&7))<<3)];
      #pragma unroll
      for (int ci=0;ci<16;ci++){
        short8 bfr = *(const short8*)&f1w[(size_t)(ci*16+l15)*256 + kk*32 + l4*8];
        acc[ci] = mfma16(af, bfr, acc[ci]);
      }
    }
    if (pass == 0){
      float p0=0.f,p1=0.f,p2=0.f,p3=0.f;
      #pragma unroll
      for (int ci=0;ci<16;ci++){
        int col = ci*16 + l15;
        float qv = sqf2[col], bv = sf1b[col];
        p0 += fmaxf(acc[ci][0]+bv,0.f)*qv;
        p1 += fmaxf(acc[ci][1]+bv,0.f)*qv;
        p2 += fmaxf(acc[ci][2]+bv,0.f)*qv;
        p3 += fmaxf(acc[ci][3]+bv,0.f)*qv;
      }
      #pragma unroll
      for (int o=8;o;o>>=1){
        p0 += __shfl_xor(p0,o); p1 += __shfl_xor(p1,o);
        p2 += __shfl_xor(p2,o); p3 += __shfl_xor(p3,o);
      }
      if (l15 == 0){
        float pj[4] = {p0,p1,p2,p3};
        #pragma unroll
        for (int j=0;j<4;j++){
          int row = w*16 + l4*4 + j;
          float dd = clampf((pj[j] + smisc[7]) * 0.0625f, -30.f, 30.f);
          dots[(size_t)bs*2048 + n0 + row] = dd;
        }
      }
      // no barrier needed here: abuf rows are wave-private for gr-write/f1-read
    } else {
      // ---- stage H -> abuf (wave-private rows), then vector store to hv ----
      #pragma unroll
      for (int ci=0;ci<16;ci++){
        int col = ci*16 + l15;
        float bv = sf1b[col];
        #pragma unroll
        for (int j=0;j<4;j++){
          int row = w*16 + l4*4 + j;
          abuf[row*256 + (((col>>3)^(row&7))<<3) + (col&7)] = f2bs(fmaxf(acc[ci][j]+bv,0.f));
        }
      }
      __syncthreads();
      #pragma unroll
      for (int i=0;i<8;i++){
        int gid = tid + i*256;
        int row = gid>>5, cg = gid&31;
        short8 av = *(const short8*)&abuf[row*256 + ((cg^(row&7))<<3)];
        *(short8*)(hv + ((size_t)(bs*2048 + n0 + row))*256 + cg*8) = av;
      }
    }
  }
}

// ---------------- softmax over s (8 slots) + per-chunk partial sums ----------------
__global__ __launch_bounds__(256) void k_softmax(const float* __restrict__ dots, float* __restrict__ aun,
                                                 float* __restrict__ sump){
  int blk = blockIdx.x;
  int b = blk >> 3, chunk = blk & 7;
  int n = chunk*256 + threadIdx.x;
  float d[8];
  #pragma unroll
  for (int s=0;s<8;s++) d[s] = dots[(size_t)(b*8+s)*2048 + n];
  float m = d[0];
  #pragma unroll
  for (int s=1;s<8;s++) m = fmaxf(m, d[s]);
  float e[8]; float sum = 0.f;
  #pragma unroll
  for (int s=0;s<8;s++){ e[s] = expf(d[s]-m); sum += e[s]; }
  float inv = 1.f/sum;
  __shared__ float red[4][8];
  int wv = threadIdx.x>>6, ln = threadIdx.x&63;
  #pragma unroll
  for (int s=0;s<8;s++){
    float a = e[s]*inv + 1e-8f;
    aun[(size_t)(b*8+s)*2048 + n] = a;
    float v = a;
    #pragma unroll
    for (int o=32;o;o>>=1) v += __shfl_xor(v,o);
    if (ln == 0) red[wv][s] = v;
  }
  __syncthreads();
  if (threadIdx.x < 8){
    int s = threadIdx.x;
    sump[(b*8+s)*8 + chunk] = red[0][s]+red[1][s]+red[2][s]+red[3][s];
  }
}

// ---------------- weighted partial reductions over n ----------------
__global__ __launch_bounds__(256) void k_c1(const float* __restrict__ aun, const short* __restrict__ hv,
    const float* __restrict__ coords, float* __restrict__ hvpart, float* __restrict__ mompart){
  int chunk = blockIdx.x, bs = blockIdx.y, b = bs >> 3;
  int t = threadIdx.x;
  int nb = chunk*256;
  __shared__ float wsm[256];
  wsm[t] = aun[(size_t)bs*2048 + nb + t];
  __syncthreads();
  float acc = 0.f;
  const short* hp = hv + ((size_t)bs*2048 + nb)*256 + t;
  #pragma unroll 4
  for (int n=0;n<256;n++) acc += wsm[n]*bf2f(hp[(size_t)n*256]);
  hvpart[(size_t)(bs*8+chunk)*256 + t] = acc;
  float wv = wsm[t];
  const float* cp = coords + ((size_t)(b*2048) + nb + t)*3;
  float c0=cp[0], c1=cp[1], c2=cp[2];
  float mv[6] = {wv*c0, wv*c1, wv*c2, wv*c0*c0, wv*c1*c1, wv*c2*c2};
  __shared__ float red[4][6];
  int wvx = t>>6, ln = t&63;
  #pragma unroll
  for (int i=0;i<6;i++){
    float v = mv[i];
    #pragma unroll
    for (int o=32;o;o>>=1) v += __shfl_xor(v,o);
    if (ln==0) red[wvx][i] = v;
  }
  __syncthreads();
  if (t<6) mompart[(bs*8+chunk)*6 + t] = red[0][t]+red[1][t]+red[2][t]+red[3][t];
}

// ---------------- final per-(b,s): updates, S_p, S_s, GRU, LN, MLP ----------------
__global__ __launch_bounds__(256) void k_c2(
    const float* __restrict__ hvpart, const float* __restrict__ mompart, const float* __restrict__ sump,
    const float* __restrict__ f2w, const float* __restrict__ f2b,
    float* __restrict__ sp, float* __restrict__ ssb,
    const float* __restrict__ wih, const float* __restrict__ whh,
    const float* __restrict__ bih, const float* __restrict__ bhh,
    const float* __restrict__ m_ng, const float* __restrict__ m_nb,
    const float* __restrict__ m1w, const float* __restrict__ m1b,
    const float* __restrict__ m2w, const float* __restrict__ m2b,
    float* __restrict__ slots){
  int bs = blockIdx.x, t = threadIdx.x;
  __shared__ float hs[256], u[256], spv[256], hln[256], r1[1024];
  __shared__ float sc[8], s4[4];
  {
    float a=0.f;
    #pragma unroll
    for (int c=0;c<8;c++) a += hvpart[(size_t)(bs*8+c)*256 + t];
    hs[t] = a;
  }
  spv[t] = slots[bs*256+t];
  if (t == 0){
    float A0=0.f;
    for (int c=0;c<8;c++) A0 += sump[bs*8+c];
    sc[0]=A0; sc[1]=A0+1e-8f;
  }
  if (t < 6){
    float mm=0.f;
    for (int c=0;c<8;c++) mm += mompart[(bs*8+c)*6 + t];
    sc[2+t] = mm;
  }
  __syncthreads();
  float A0 = sc[0], denom = sc[1];
  if (t < 3){
    float A1 = sc[2+t], A2 = sc[5+t];
    float p = A1/denom;
    float var = (A2 - 2.f*p*A1 + p*p*A0)/denom + 1e-6f;
    float sv = clampf(sqrtf(var), 0.2f, 5.f);
    sp[bs*3+t] = p; ssb[bs*3+t] = sv;
  }
  {
    float dd = 0.f;
    const float4* fr = (const float4*)(f2w + (size_t)t*256);
    for (int h4=0; h4<64; ++h4){
      float4 w4 = fr[h4];
      dd += hs[h4*4+0]*w4.x + hs[h4*4+1]*w4.y + hs[h4*4+2]*w4.z + hs[h4*4+3]*w4.w;
    }
    u[t] = n2nf((dd + A0*f2b[t])/denom);
  }
  __syncthreads();
  float gi[3], gh[3];
  #pragma unroll 1
  for (int part=0; part<3; ++part){
    int o = part*256 + t;
    const float4* wr = (const float4*)(wih + (size_t)o*256);
    const float4* hr = (const float4*)(whh + (size_t)o*256);
    float si = bih[o], sh = bhh[o];
    for (int d4=0; d4<64; ++d4){
      float4 a4 = wr[d4], b4 = hr[d4];
      si += u[d4*4+0]*a4.x + u[d4*4+1]*a4.y + u[d4*4+2]*a4.z + u[d4*4+3]*a4.w;
      sh += spv[d4*4+0]*b4.x + spv[d4*4+1]*b4.y + spv[d4*4+2]*b4.z + spv[d4*4+3]*b4.w;
    }
    gi[part]=si; gh[part]=sh;
  }
  float rg = sigmoidf(gi[0]+gh[0]);
  float zg = sigmoidf(gi[1]+gh[1]);
  float nn = tanhf(gi[2] + rg*gh[2]);
  float hnew = (1.f-zg)*nn + zg*spv[t];
  float m = blkSum(hnew, s4, t)*(1.f/256.f);
  float dv = hnew - m;
  float var = blkSum(dv*dv, s4, t)*(1.f/256.f);
  hln[t] = dv*(1.f/sqrtf(var+1e-5f))*m_ng[t] + m_nb[t];
  __syncthreads();
  #pragma unroll 1
  for (int oi=0; oi<4; ++oi){
    int o = t*4 + oi;
    const float4* mr = (const float4*)(m1w + (size_t)o*256);
    float s = m1b[o];
    for (int d4=0; d4<64; ++d4){
      float4 a4 = mr[d4];
      s += hln[d4*4+0]*a4.x + hln[d4*4+1]*a4.y + hln[d4*4+2]*a4.z + hln[d4*4+3]*a4.w;
    }
    r1[o] = fmaxf(s, 0.f);
  }
  __syncthreads();
  {
    const float4* mr = (const float4*)(m2w + (size_t)t*1024);
    float s = m2b[t];
    for (int o4=0; o4<256; ++o4){
      float4 a4 = mr[o4];
      s += r1[o4*4+0]*a4.x + r1[o4*4+1]*a4.y + r1[o4*4+2]*a4.z + r1[o4*4+3]*a4.w;
    }
    slots[bs*256+t] = n2nf(hnew + s);
  }
}

__global__ __launch_bounds__(256) void k_attn_out(const float* __restrict__ aun, const float* __restrict__ sump,
                                                  float* __restrict__ outp){
  int g = blockIdx.x*256 + threadIdx.x;
  int bs = g >> 11;
  __shared__ float dsh;
  if (threadIdx.x == 0){
    float s=0.f;
    for (int c=0;c<8;c++) s += sump[bs*8+c];
    dsh = s + 1e-8f;
  }
  __syncthreads();
  outp[g] = aun[g] / dsh;
}

__global__ __launch_bounds__(256) void k_final(const float* __restrict__ slots,
    const float* __restrict__ fw, const float* __restrict__ fb, float* __restrict__ outp){
  int bs = blockIdx.x, t = threadIdx.x;
  __shared__ float sl[256];
  sl[t] = slots[bs*256+t];
  __syncthreads();
  const float4* fr = (const float4*)(fw + (size_t)t*256);
  float s = fb[t];
  for (int d4=0; d4<64; ++d4){
    float4 w4 = fr[d4];
    s += sl[d4*4+0]*w4.x + sl[d4*4+1]*w4.y + sl[d4*4+2]*w4.z + sl[d4*4+3]*w4.w;
  }
  outp[bs*256+t] = s;
}

extern "C" void kernel_launch(void* const* d_in, const int* in_sizes, int n_in,
                              void* d_out, int out_size, void* d_ws, size_t ws_size,
                              hipStream_t stream){
  const float* p_inputs = (const float*)d_in[0];
  const float* p_coords = (const float*)d_in[1];
  const float* p_slotsp = (const float*)d_in[2];
  const float* p_Ss0 = (const float*)d_in[3];
  const float* p_Sp0 = (const float*)d_in[4];
  const float* p_Qw  = (const float*)d_in[5];
  const float* p_Kw  = (const float*)d_in[6];
  const float* p_Vw  = (const float*)d_in[7];
  const float* p_gw  = (const float*)d_in[8];
  const float* p_gb  = (const float*)d_in[9];
  const float* p_f1w = (const float*)d_in[10];
  const float* p_f1b = (const float*)d_in[11];
  const float* p_f2w = (const float*)d_in[12];
  const float* p_f2b = (const float*)d_in[13];
  const float* p_ng  = (const float*)d_in[14];
  const float* p_nb  = (const float*)d_in[15];
  const float* p_wih = (const float*)d_in[16];
  const float* p_whh = (const float*)d_in[17];
  const float* p_bih = (const float*)d_in[18];
  const float* p_bhh = (const float*)d_in[19];
  const float* p_mng = (const float*)d_in[20];
  const float* p_mnb = (const float*)d_in[21];
  const float* p_m1w = (const float*)d_in[22];
  const float* p_m1b = (const float*)d_in[23];
  const float* p_m2w = (const float*)d_in[24];
  const float* p_m2b = (const float*)d_in[25];
  const float* p_i0g = (const float*)d_in[26];
  const float* p_i0b = (const float*)d_in[27];
  const float* p_i1w = (const float*)d_in[28];
  const float* p_i1b = (const float*)d_in[29];
  const float* p_i2w = (const float*)d_in[30];
  const float* p_i2b = (const float*)d_in[31];
  const float* p_i3g = (const float*)d_in[32];
  const float* p_i3b = (const float*)d_in[33];
  const float* p_fw  = (const float*)d_in[34];
  const float* p_fb  = (const float*)d_in[35];

  char* ws = (char*)d_ws;
  size_t off = 0;
  auto alloc = [&](size_t bytes)->char*{
    char* p = ws + off;
    off = (off + bytes + 255) & ~(size_t)255;
    return p;
  };
  short* xln   = (short*)alloc(8192ull*768*2);
  short* h1    = (short*)alloc(8192ull*768*2);
  float* x2    = (float*)alloc(8192ull*256*4);
  short* xenc  = (short*)alloc(8192ull*256*2);
  short* kxb   = (short*)alloc(8192ull*256*2);
  short* vxb   = (short*)alloc(8192ull*256*2);
  short* hvb   = (short*)alloc(32ull*2048*256*2);
  float* dots  = (float*)alloc(32ull*2048*4);
  float* aun   = (float*)alloc(32ull*2048*4);
  float* sump  = (float*)alloc(32*8*4);
  float* hvpart= (float*)alloc(32ull*8*256*4);
  float* mompart=(float*)alloc(32*8*6*4);
  short* i1wb  = (short*)alloc(768ull*768*2);
  short* i2wb  = (short*)alloc(256ull*768*2);
  short* kwb   = (short*)alloc(256ull*256*2);
  short* vwb   = (short*)alloc(256ull*256*2);
  short* f1wb  = (short*)alloc(256ull*256*2);
  short* gwp   = (short*)alloc(256ull*64*2);
  float* slots = (float*)alloc(32*256*4);
  float* qf2   = (float*)alloc(32*256*4);
  float* qbv   = (float*)alloc(32*4);
  float* spb   = (float*)alloc(32*3*4);
  float* ssbuf = (float*)alloc(32*3*4);

  auto cvt = [&](const float* s, short* dst, int n){
    k_convert<<<(n+255)/256, 256, 0, stream>>>(s, dst, n);
  };
  cvt(p_i1w, i1wb, 768*768);
  cvt(p_i2w, i2wb, 256*768);
  cvt(p_Kw,  kwb,  256*256);
  cvt(p_Vw,  vwb,  256*256);
  cvt(p_f1w, f1wb, 256*256);
  k_prep_gwp<<<64,256,0,stream>>>(p_gw, p_gb, gwp);
  k_init<<<32,256,0,stream>>>(p_slotsp, p_Sp0, p_Ss0, slots, spb, ssbuf);

  k_ln768<<<8192,256,0,stream>>>(p_inputs, p_i0g, p_i0b, xln);
  k_gemm<<<dim3(128,6),256,0,stream>>>(xln, i1wb, p_i1b, h1, 768, 768, 1|2|4);
  k_gemm<<<dim3(128,2),256,0,stream>>>(h1, i2wb, p_i2b, x2, 256, 768, 1);
  k_ln256<<<8192,256,0,stream>>>(x2, p_i3g, p_i3b, xenc);
  k_gemm<<<dim3(128,2),256,0,stream>>>(xenc, kwb, nullptr, kxb, 256, 256, 4);
  k_gemm<<<dim3(128,2),256,0,stream>>>(xenc, vwb, nullptr, vxb, 256, 256, 4);

  float* outf = (float*)d_out;
  for (int t=0;t<4;t++){
    k_qprep<<<32,256,0,stream>>>(slots, p_ng, p_nb, p_Qw, p_f2w, p_f2b, qf2, qbv);
    k_isa_a<<<dim3(32,32),256,0,stream>>>(p_coords, spb, ssbuf, gwp, kxb, vxb, f1wb, p_f1b, qf2, qbv, dots, hvb, (t<3)?2:1);
    k_softmax<<<32,256,0,stream>>>(dots, aun, sump);
    if (t < 3){
      k_c1<<<dim3(8,32),256,0,stream>>>(aun, hvb, p_coords, hvpart, mompart);
      k_c2<<<32,256,0,stream>>>(hvpart, mompart, sump, p_f2w, p_f2b, spb, ssbuf,
                                p_wih, p_whh, p_bih, p_bhh, p_mng, p_mnb,
                                p_m1w, p_m1b, p_m2w, p_m2b, slots);
    } else {
      k_attn_out<<<256,256,0,stream>>>(aun, sump, outf + 8192);
    }
  }
  k_final<<<32,256,0,stream>>>(slots, p_fw, p_fb, outf);
}

// Round 9
// 1335.951 us; speedup vs baseline: 1.1137x; 1.1137x over previous
//
#include <hip/hip_runtime.h>
#include <math.h>

#define DEVI __device__ __forceinline__

typedef __attribute__((ext_vector_type(8))) short short8;
typedef __attribute__((ext_vector_type(4))) float f32x4;

DEVI float bf2f(short u){ unsigned v = ((unsigned)(unsigned short)u) << 16; return __builtin_bit_cast(float, v); }
DEVI short f2bs(float f){
  unsigned x = __builtin_bit_cast(unsigned, f);
  unsigned r = (x + 0x7fffu + ((x >> 16) & 1u)) >> 16;
  return (short)(unsigned short)r;
}
DEVI float clampf(float x, float lo, float hi){ return fminf(fmaxf(x, lo), hi); }
DEVI float n2nf(float x){
  if (x != x) return 0.f;
  if (x == INFINITY) return 1.f;
  if (x == -INFINITY) return -1.f;
  return x;
}
DEVI float sigmoidf(float x){ return 1.f/(1.f+expf(-x)); }
DEVI f32x4 mfma16(short8 a, short8 b, f32x4 c){ return __builtin_amdgcn_mfma_f32_16x16x32_bf16(a,b,c,0,0,0); }

DEVI float blkSum(float v, float* s4, int tid){
  #pragma unroll
  for (int o=32;o;o>>=1) v += __shfl_xor(v,o);
  __syncthreads();
  if ((tid&63)==0) s4[tid>>6] = v;
  __syncthreads();
  return s4[0]+s4[1]+s4[2]+s4[3];
}

// sn=LN(sl); q=sn@Qw^T; qf2=q@f2w; qbv=q.f2b   (shared LDS buffers sn,q passed in)
DEVI void qprep_body(float sl, int bs, int t,
    const float* __restrict__ ng, const float* __restrict__ nbv, const float* __restrict__ Qw,
    const float* __restrict__ f2w, const float* __restrict__ f2b,
    float* __restrict__ qf2, float* __restrict__ qbv,
    float* sn, float* q, float* s4){
  float m = blkSum(sl, s4, t)*(1.f/256.f);
  float d = sl - m;
  float var = blkSum(d*d, s4, t)*(1.f/256.f);
  sn[t] = d*(1.f/sqrtf(var+1e-5f))*ng[t] + nbv[t];
  __syncthreads();
  {
    const float4* qr = (const float4*)(Qw + (size_t)t*256);
    float s = 0.f;
    for (int d4=0; d4<64; ++d4){
      float4 w4 = qr[d4];
      s += sn[d4*4+0]*w4.x + sn[d4*4+1]*w4.y + sn[d4*4+2]*w4.z + sn[d4*4+3]*w4.w;
    }
    q[t] = s;
  }
  __syncthreads();
  {
    float s = 0.f;
    for (int o=0;o<256;o++) s += q[o]*f2w[(size_t)o*256 + t];
    qf2[bs*256+t] = s;
  }
  float tot = blkSum(q[t]*f2b[t], s4, t);
  if (t==0) qbv[bs] = tot;
}

// ---------------- utility kernels ----------------
__global__ void k_convert(const float* __restrict__ s, short* __restrict__ d, int n){
  int i = blockIdx.x*256 + threadIdx.x;
  if (i < n) d[i] = f2bs(s[i]);
}

__global__ void k_prep_gwp(const float* __restrict__ gw, const float* __restrict__ gb, short* __restrict__ gwp){
  int i = blockIdx.x*256 + threadIdx.x;   // 0..16383
  int d = i >> 6, c = i & 63;
  float v = (c < 39) ? gw[d*39 + c] : (c == 39 ? gb[d] : 0.f);
  gwp[i] = f2bs(v);
}

__global__ __launch_bounds__(256) void k_init(const float* __restrict__ slots_p, const float* __restrict__ Sp0,
                       const float* __restrict__ Ss0,
                       float* __restrict__ slots, float* __restrict__ sp, float* __restrict__ ssb,
                       const float* __restrict__ ng, const float* __restrict__ nbv, const float* __restrict__ Qw,
                       const float* __restrict__ f2w, const float* __restrict__ f2b,
                       float* __restrict__ qf2, float* __restrict__ qbv){
  int bs = blockIdx.x, t = threadIdx.x, s = bs & 7;
  __shared__ float sn[256], q[256], s4[4];
  float sl = slots_p[s*256+t];
  slots[bs*256+t] = sl;
  if (t < 3){ sp[bs*3+t] = Sp0[s*3+t]; ssb[bs*3+t] = Ss0[s*3+t]; }
  qprep_body(sl, bs, t, ng, nbv, Qw, f2w, f2b, qf2, qbv, sn, q, s4);
}

__global__ __launch_bounds__(256) void k_ln768(const float* __restrict__ in, const float* __restrict__ g,
                                               const float* __restrict__ bt, short* __restrict__ out){
  int r = blockIdx.x, t = threadIdx.x;
  __shared__ float s4[4];
  const float* row = in + (size_t)r*768;
  float x0=row[t], x1=row[256+t], x2=row[512+t];
  float m = blkSum(x0+x1+x2, s4, t) * (1.f/768.f);
  float d0=x0-m, d1=x1-m, d2=x2-m;
  float var = blkSum(d0*d0+d1*d1+d2*d2, s4, t) * (1.f/768.f);
  float rstd = 1.f/sqrtf(var + 1e-5f);
  short* orow = out + (size_t)r*768;
  orow[t]     = f2bs(d0*rstd*g[t]     + bt[t]);
  orow[256+t] = f2bs(d1*rstd*g[256+t] + bt[256+t]);
  orow[512+t] = f2bs(d2*rstd*g[512+t] + bt[512+t]);
}

__global__ __launch_bounds__(256) void k_ln256(const float* __restrict__ in, const float* __restrict__ g,
                                               const float* __restrict__ bt, short* __restrict__ out){
  int r = blockIdx.x, t = threadIdx.x;
  __shared__ float s4[4];
  float x = in[(size_t)r*256 + t];
  float m = blkSum(x, s4, t) * (1.f/256.f);
  float d = x - m;
  float var = blkSum(d*d, s4, t) * (1.f/256.f);
  out[(size_t)r*256 + t] = f2bs(d*(1.f/sqrtf(var+1e-5f))*g[t] + bt[t]);
}

// ---------------- generic MFMA GEMM (runtime KT/flags) ----------------
// flags: 1=bias, 2=relu, 4=bf16out
__global__ __launch_bounds__(256) void k_gemm(const short* __restrict__ A, const short* __restrict__ W,
                                              const float* __restrict__ bias, void* __restrict__ outp,
                                              int ldo, int KT, int flags){
  const int w = threadIdx.x>>6, l = threadIdx.x&63, l15 = l&15, l4 = l>>4;
  const int row0 = blockIdx.x*64 + w*16;
  const int col0 = blockIdx.y*128;
  f32x4 acc[8];
  #pragma unroll
  for (int i=0;i<8;i++) acc[i] = (f32x4)(0.f);
  const short* Ap  = A + (size_t)(row0+l15)*KT + l4*8;
  const short* Wp0 = W + (size_t)(col0+l15)*KT + l4*8;
  #pragma unroll 2
  for (int kk=0; kk<KT/32; ++kk){
    short8 af = *(const short8*)(Ap + kk*32);
    #pragma unroll
    for (int ci=0; ci<8; ++ci){
      short8 bfr = *(const short8*)(Wp0 + (size_t)ci*16*KT + kk*32);
      acc[ci] = mfma16(af, bfr, acc[ci]);
    }
  }
  #pragma unroll
  for (int ci=0; ci<8; ++ci){
    int col = col0 + ci*16 + l15;
    float bv = (flags&1) ? bias[col] : 0.f;
    #pragma unroll
    for (int j=0;j<4;j++){
      int row = row0 + l4*4 + j;
      float v = acc[ci][j] + bv;
      if (flags&2) v = fmaxf(v, 0.f);
      if (flags&4) ((short*)outp)[(size_t)row*ldo + col] = f2bs(v);
      else         ((float*)outp)[(size_t)row*ldo + col] = v;
    }
  }
}

// ---------------- the big fused kernel ----------------
// grid (N/64, B*S), 256 threads. Per wave: 16 rows x 256 cols, ci chunked by 2.
__global__ __launch_bounds__(256, 3) void k_isa_a(
    const float* __restrict__ coords, const float* __restrict__ sp, const float* __restrict__ ssb,
    const short* __restrict__ gwp, const short* __restrict__ kx, const short* __restrict__ vx,
    const short* __restrict__ f1w, const float* __restrict__ f1b,
    const float* __restrict__ qf2, const float* __restrict__ qbv,
    float* __restrict__ dots, short* __restrict__ hv, int npass){
  __shared__ __align__(16) short ffs[64*64];
  __shared__ __align__(16) short abuf[64*256];
  __shared__ float sf1b[256];
  __shared__ float sqf2[256];
  __shared__ float smisc[8];
  const int tid = threadIdx.x;
  const int bs = blockIdx.y;
  const int b  = bs >> 3;
  const int n0 = blockIdx.x * 64;

  sf1b[tid] = f1b[tid];
  sqf2[tid] = qf2[bs*256 + tid];
  if (tid < 3){
    smisc[tid] = sp[bs*3+tid];
    float sv = ssb[bs*3+tid];
    float sa = clampf(sv, 0.3f, 5.f) + 0.1f;
    smisc[4+tid] = 1.f/(sa*5.f + 1e-4f);
  }
  if (tid == 7) smisc[7] = qbv[bs];
  __syncthreads();

  // fourier features into ffs
  {
    const float FRQ[6] = {6.283185307179586f,12.566370614359172f,25.132741228718345f,
                          50.26548245743669f,100.53096491487338f,201.06192982974676f};
    int n  = tid >> 2;
    int cb = (tid & 3) * 16;
    float rel[3];
    #pragma unroll
    for (int i=0;i<3;i++){
      float c = coords[((size_t)(b*2048 + n0 + n))*3 + i];
      rel[i] = clampf((c - smisc[i]) * smisc[4+i], -3.f, 3.f);
    }
    #pragma unroll 1
    for (int cc=0; cc<16; ++cc){
      int c = cb + cc;
      float v;
      if (c < 3) v = rel[c];
      else if (c < 39){
        int q = c-3; int i = q/12; int j = (q%12)>>1;
        float ang = rel[i]*FRQ[j];
        v = (q & 1) ? __cosf(ang) : __sinf(ang);
      }
      else if (c == 39) v = 1.f;
      else v = 0.f;
      ffs[n*64 + (((c>>3)^(n&7))<<3) + (c&7)] = f2bs(v);
    }
  }
  __syncthreads();

  const int w = tid>>6, l = tid&63, l15 = l&15, l4 = l>>4;
  const int ar = w*16 + l15;           // A-row this lane reads (wave-private)

  #pragma unroll 1
  for (int pass = 0; pass < npass; ++pass){
    // ---- gr GEMM (K=64), ci chunked by 2, write bf16 to abuf (swizzled, wave-own rows) ----
    {
      short8 ag0 = *(const short8*)&ffs[ar*64 + ((l4 ^ (ar&7))<<3)];
      short8 ag1 = *(const short8*)&ffs[ar*64 + (((4+l4) ^ (ar&7))<<3)];
      #pragma unroll 2
      for (int cc=0; cc<8; ++cc){
        int c0 = (2*cc)*16 + l15, c1 = (2*cc+1)*16 + l15;
        f32x4 a0 = (f32x4)(0.f), a1 = (f32x4)(0.f);
        a0 = mfma16(ag0, *(const short8*)&gwp[(size_t)c0*64 + l4*8], a0);
        a0 = mfma16(ag1, *(const short8*)&gwp[(size_t)c0*64 + 32 + l4*8], a0);
        a1 = mfma16(ag0, *(const short8*)&gwp[(size_t)c1*64 + l4*8], a1);
        a1 = mfma16(ag1, *(const short8*)&gwp[(size_t)c1*64 + 32 + l4*8], a1);
        #pragma unroll
        for (int j=0;j<4;j++){
          int row = w*16 + l4*4 + j;
          abuf[row*256 + (((c0>>3)^(row&7))<<3) + (c0&7)] = f2bs(a0[j]);
          abuf[row*256 + (((c1>>3)^(row&7))<<3) + (c1&7)] = f2bs(a1[j]);
        }
      }
    }
    __syncthreads();
    // ---- abuf += Kx|Vx  (vectorized short8 RMW) ----
    {
      const short* srcb = pass ? vx : kx;
      #pragma unroll
      for (int i=0;i<8;i++){
        int gid = tid + i*256;
        int row = gid>>5, cg = gid&31;
        short8 sv = *(const short8*)(srcb + ((size_t)(b*2048 + n0 + row))*256 + cg*8);
        short* ap = &abuf[row*256 + ((cg^(row&7))<<3)];
        short8 av = *(const short8*)ap;
        short8 ov;
        #pragma unroll
        for (int e=0;e<8;e++) ov[e] = f2bs(bf2f(av[e]) + bf2f(sv[e]));
        *(short8*)ap = ov;
      }
    }
    __syncthreads();
    // ---- f1 GEMM (K=256): cache A-fragments in regs, ci chunked by 2 ----
    short8 af[8];
    #pragma unroll
    for (int kk=0;kk<8;kk++)
      af[kk] = *(const short8*)&abuf[ar*256 + (((kk*4+l4) ^ (ar&7))<<3)];

    if (pass == 0){
      float p0=0.f,p1=0.f,p2=0.f,p3=0.f;
      #pragma unroll 2
      for (int cc=0; cc<8; ++cc){
        int c0 = (2*cc)*16 + l15, c1 = (2*cc+1)*16 + l15;
        f32x4 a0 = (f32x4)(0.f), a1 = (f32x4)(0.f);
        #pragma unroll
        for (int kk=0;kk<8;kk++){
          a0 = mfma16(af[kk], *(const short8*)&f1w[(size_t)c0*256 + kk*32 + l4*8], a0);
          a1 = mfma16(af[kk], *(const short8*)&f1w[(size_t)c1*256 + kk*32 + l4*8], a1);
        }
        float q0=sqf2[c0], b0=sf1b[c0], q1=sqf2[c1], b1=sf1b[c1];
        p0 += fmaxf(a0[0]+b0,0.f)*q0 + fmaxf(a1[0]+b1,0.f)*q1;
        p1 += fmaxf(a0[1]+b0,0.f)*q0 + fmaxf(a1[1]+b1,0.f)*q1;
        p2 += fmaxf(a0[2]+b0,0.f)*q0 + fmaxf(a1[2]+b1,0.f)*q1;
        p3 += fmaxf(a0[3]+b0,0.f)*q0 + fmaxf(a1[3]+b1,0.f)*q1;
      }
      #pragma unroll
      for (int o=8;o;o>>=1){
        p0 += __shfl_xor(p0,o); p1 += __shfl_xor(p1,o);
        p2 += __shfl_xor(p2,o); p3 += __shfl_xor(p3,o);
      }
      if (l15 == 0){
        float pj[4] = {p0,p1,p2,p3};
        #pragma unroll
        for (int j=0;j<4;j++){
          int row = w*16 + l4*4 + j;
          float dd = clampf((pj[j] + smisc[7]) * 0.0625f, -30.f, 30.f);
          dots[(size_t)bs*2048 + n0 + row] = dd;
        }
      }
    } else {
      #pragma unroll 2
      for (int cc=0; cc<8; ++cc){
        int c0 = (2*cc)*16 + l15, c1 = (2*cc+1)*16 + l15;
        f32x4 a0 = (f32x4)(0.f), a1 = (f32x4)(0.f);
        #pragma unroll
        for (int kk=0;kk<8;kk++){
          a0 = mfma16(af[kk], *(const short8*)&f1w[(size_t)c0*256 + kk*32 + l4*8], a0);
          a1 = mfma16(af[kk], *(const short8*)&f1w[(size_t)c1*256 + kk*32 + l4*8], a1);
        }
        float b0=sf1b[c0], b1=sf1b[c1];
        #pragma unroll
        for (int j=0;j<4;j++){
          int row = w*16 + l4*4 + j;
          abuf[row*256 + (((c0>>3)^(row&7))<<3) + (c0&7)] = f2bs(fmaxf(a0[j]+b0,0.f));
          abuf[row*256 + (((c1>>3)^(row&7))<<3) + (c1&7)] = f2bs(fmaxf(a1[j]+b1,0.f));
        }
      }
      __syncthreads();
      #pragma unroll
      for (int i=0;i<8;i++){
        int gid = tid + i*256;
        int row = gid>>5, cg = gid&31;
        short8 av = *(const short8*)&abuf[row*256 + ((cg^(row&7))<<3)];
        *(short8*)(hv + ((size_t)(bs*2048 + n0 + row))*256 + cg*8) = av;
      }
    }
  }
}

// ---------------- softmax (t=3 only, feeds attn output) ----------------
__global__ __launch_bounds__(256) void k_softmax(const float* __restrict__ dots, float* __restrict__ aun,
                                                 float* __restrict__ sump){
  int blk = blockIdx.x;
  int b = blk >> 3, chunk = blk & 7;
  int n = chunk*256 + threadIdx.x;
  float d[8];
  #pragma unroll
  for (int s=0;s<8;s++) d[s] = dots[(size_t)(b*8+s)*2048 + n];
  float m = d[0];
  #pragma unroll
  for (int s=1;s<8;s++) m = fmaxf(m, d[s]);
  float e[8]; float sum = 0.f;
  #pragma unroll
  for (int s=0;s<8;s++){ e[s] = expf(d[s]-m); sum += e[s]; }
  float inv = 1.f/sum;
  __shared__ float red[4][8];
  int wv = threadIdx.x>>6, ln = threadIdx.x&63;
  #pragma unroll
  for (int s=0;s<8;s++){
    float a = e[s]*inv + 1e-8f;
    aun[(size_t)(b*8+s)*2048 + n] = a;
    float v = a;
    #pragma unroll
    for (int o=32;o;o>>=1) v += __shfl_xor(v,o);
    if (ln == 0) red[wv][s] = v;
  }
  __syncthreads();
  if (threadIdx.x < 8){
    int s = threadIdx.x;
    sump[(b*8+s)*8 + chunk] = red[0][s]+red[1][s]+red[2][s]+red[3][s];
  }
}

// ---------------- fused softmax + weighted partial reductions (t<3) ----------------
__global__ __launch_bounds__(256) void k_c1(const float* __restrict__ dots, const short* __restrict__ hv,
    const float* __restrict__ coords, float* __restrict__ hvpart, float* __restrict__ mompart,
    float* __restrict__ sump){
  int chunk = blockIdx.x, bs = blockIdx.y, b = bs >> 3, so = bs & 7;
  int t = threadIdx.x;
  int nb = chunk*256;
  __shared__ float wsm[256];
  // inline softmax over s at n = nb+t
  {
    float d[8];
    #pragma unroll
    for (int s=0;s<8;s++) d[s] = dots[(size_t)(b*8+s)*2048 + nb + t];
    float m = d[0];
    #pragma unroll
    for (int s=1;s<8;s++) m = fmaxf(m, d[s]);
    float sum = 0.f; float eo = 0.f;
    #pragma unroll
    for (int s=0;s<8;s++){ float e = expf(d[s]-m); sum += e; if (s==so) eo = e; }
    wsm[t] = eo/sum + 1e-8f;
  }
  __syncthreads();
  float acc = 0.f;
  const short* hp = hv + ((size_t)bs*2048 + nb)*256 + t;
  #pragma unroll 4
  for (int n=0;n<256;n++) acc += wsm[n]*bf2f(hp[(size_t)n*256]);
  hvpart[(size_t)(bs*8+chunk)*256 + t] = acc;
  float wv = wsm[t];
  const float* cp = coords + ((size_t)(b*2048) + nb + t)*3;
  float c0=cp[0], c1=cp[1], c2=cp[2];
  float mv[7] = {wv*c0, wv*c1, wv*c2, wv*c0*c0, wv*c1*c1, wv*c2*c2, wv};
  __shared__ float red[4][7];
  int wvx = t>>6, ln = t&63;
  #pragma unroll
  for (int i=0;i<7;i++){
    float v = mv[i];
    #pragma unroll
    for (int o=32;o;o>>=1) v += __shfl_xor(v,o);
    if (ln==0) red[wvx][i] = v;
  }
  __syncthreads();
  if (t<7){
    float r = red[0][t]+red[1][t]+red[2][t]+red[3][t];
    if (t<6) mompart[(bs*8+chunk)*6 + t] = r;
    else     sump[bs*8 + chunk] = r;
  }
}

// ---------------- final per-(b,s): updates, S_p, S_s, GRU, LN, MLP, then qprep for next iter ----------------
__global__ __launch_bounds__(256) void k_c2(
    const float* __restrict__ hvpart, const float* __restrict__ mompart, const float* __restrict__ sump,
    const float* __restrict__ f2w, const float* __restrict__ f2b,
    float* __restrict__ sp, float* __restrict__ ssb,
    const float* __restrict__ wih, const float* __restrict__ whh,
    const float* __restrict__ bih, const float* __restrict__ bhh,
    const float* __restrict__ m_ng, const float* __restrict__ m_nb,
    const float* __restrict__ m1w, const float* __restrict__ m1b,
    const float* __restrict__ m2w, const float* __restrict__ m2b,
    float* __restrict__ slots,
    const float* __restrict__ ng, const float* __restrict__ nbv, const float* __restrict__ Qw,
    float* __restrict__ qf2, float* __restrict__ qbv){
  int bs = blockIdx.x, t = threadIdx.x;
  __shared__ float hs[256], u[256], spv[256], hln[256], r1[1024];
  __shared__ float sc[8], s4[4];
  {
    float a=0.f;
    #pragma unroll
    for (int c=0;c<8;c++) a += hvpart[(size_t)(bs*8+c)*256 + t];
    hs[t] = a;
  }
  spv[t] = slots[bs*256+t];
  if (t == 0){
    float A0=0.f;
    for (int c=0;c<8;c++) A0 += sump[bs*8+c];
    sc[0]=A0; sc[1]=A0+1e-8f;
  }
  if (t < 6){
    float mm=0.f;
    for (int c=0;c<8;c++) mm += mompart[(bs*8+c)*6 + t];
    sc[2+t] = mm;
  }
  __syncthreads();
  float A0 = sc[0], denom = sc[1];
  if (t < 3){
    float A1 = sc[2+t], A2 = sc[5+t];
    float p = A1/denom;
    float var = (A2 - 2.f*p*A1 + p*p*A0)/denom + 1e-6f;
    float sv = clampf(sqrtf(var), 0.2f, 5.f);
    sp[bs*3+t] = p; ssb[bs*3+t] = sv;
  }
  {
    float dd = 0.f;
    const float4* fr = (const float4*)(f2w + (size_t)t*256);
    for (int h4=0; h4<64; ++h4){
      float4 w4 = fr[h4];
      dd += hs[h4*4+0]*w4.x + hs[h4*4+1]*w4.y + hs[h4*4+2]*w4.z + hs[h4*4+3]*w4.w;
    }
    u[t] = n2nf((dd + A0*f2b[t])/denom);
  }
  __syncthreads();
  float gi[3], gh[3];
  #pragma unroll 1
  for (int part=0; part<3; ++part){
    int o = part*256 + t;
    const float4* wr = (const float4*)(wih + (size_t)o*256);
    const float4* hr = (const float4*)(whh + (size_t)o*256);
    float si = bih[o], sh = bhh[o];
    for (int d4=0; d4<64; ++d4){
      float4 a4 = wr[d4], b4 = hr[d4];
      si += u[d4*4+0]*a4.x + u[d4*4+1]*a4.y + u[d4*4+2]*a4.z + u[d4*4+3]*a4.w;
      sh += spv[d4*4+0]*b4.x + spv[d4*4+1]*b4.y + spv[d4*4+2]*b4.z + spv[d4*4+3]*b4.w;
    }
    gi[part]=si; gh[part]=sh;
  }
  float rg = sigmoidf(gi[0]+gh[0]);
  float zg = sigmoidf(gi[1]+gh[1]);
  float nn = tanhf(gi[2] + rg*gh[2]);
  float hnew = (1.f-zg)*nn + zg*spv[t];
  float m = blkSum(hnew, s4, t)*(1.f/256.f);
  float dv = hnew - m;
  float var = blkSum(dv*dv, s4, t)*(1.f/256.f);
  hln[t] = dv*(1.f/sqrtf(var+1e-5f))*m_ng[t] + m_nb[t];
  __syncthreads();
  #pragma unroll 1
  for (int oi=0; oi<4; ++oi){
    int o = t*4 + oi;
    const float4* mr = (const float4*)(m1w + (size_t)o*256);
    float s = m1b[o];
    for (int d4=0; d4<64; ++d4){
      float4 a4 = mr[d4];
      s += hln[d4*4+0]*a4.x + hln[d4*4+1]*a4.y + hln[d4*4+2]*a4.z + hln[d4*4+3]*a4.w;
    }
    r1[o] = fmaxf(s, 0.f);
  }
  __syncthreads();
  float sl;
  {
    const float4* mr = (const float4*)(m2w + (size_t)t*1024);
    float s = m2b[t];
    for (int o4=0; o4<256; ++o4){
      float4 a4 = mr[o4];
      s += r1[o4*4+0]*a4.x + r1[o4*4+1]*a4.y + r1[o4*4+2]*a4.z + r1[o4*4+3]*a4.w;
    }
    sl = n2nf(hnew + s);
    slots[bs*256+t] = sl;
  }
  // qprep for next iteration (reuse hs/u as sn/q scratch; blkSum's barrier orders prior reads)
  qprep_body(sl, bs, t, ng, nbv, Qw, f2w, f2b, qf2, qbv, hs, u, s4);
}

__global__ __launch_bounds__(256) void k_attn_out(const float* __restrict__ aun, const float* __restrict__ sump,
                                                  float* __restrict__ outp){
  int g = blockIdx.x*256 + threadIdx.x;
  int bs = g >> 11;
  __shared__ float dsh;
  if (threadIdx.x == 0){
    float s=0.f;
    for (int c=0;c<8;c++) s += sump[bs*8+c];
    dsh = s + 1e-8f;
  }
  __syncthreads();
  outp[g] = aun[g] / dsh;
}

__global__ __launch_bounds__(256) void k_final(const float* __restrict__ slots,
    const float* __restrict__ fw, const float* __restrict__ fb, float* __restrict__ outp){
  int bs = blockIdx.x, t = threadIdx.x;
  __shared__ float sl[256];
  sl[t] = slots[bs*256+t];
  __syncthreads();
  const float4* fr = (const float4*)(fw + (size_t)t*256);
  float s = fb[t];
  for (int d4=0; d4<64; ++d4){
    float4 w4 = fr[d4];
    s += sl[d4*4+0]*w4.x + sl[d4*4+1]*w4.y + sl[d4*4+2]*w4.z + sl[d4*4+3]*w4.w;
  }
  outp[bs*256+t] = s;
}

extern "C" void kernel_launch(void* const* d_in, const int* in_sizes, int n_in,
                              void* d_out, int out_size, void* d_ws, size_t ws_size,
                              hipStream_t stream){
  const float* p_inputs = (const float*)d_in[0];
  const float* p_coords = (const float*)d_in[1];
  const float* p_slotsp = (const float*)d_in[2];
  const float* p_Ss0 = (const float*)d_in[3];
  const float* p_Sp0 = (const float*)d_in[4];
  const float* p_Qw  = (const float*)d_in[5];
  const float* p_Kw  = (const float*)d_in[6];
  const float* p_Vw  = (const float*)d_in[7];
  const float* p_gw  = (const float*)d_in[8];
  const float* p_gb  = (const float*)d_in[9];
  const float* p_f1w = (const float*)d_in[10];
  const float* p_f1b = (const float*)d_in[11];
  const float* p_f2w = (const float*)d_in[12];
  const float* p_f2b = (const float*)d_in[13];
  const float* p_ng  = (const float*)d_in[14];
  const float* p_nb  = (const float*)d_in[15];
  const float* p_wih = (const float*)d_in[16];
  const float* p_whh = (const float*)d_in[17];
  const float* p_bih = (const float*)d_in[18];
  const float* p_bhh = (const float*)d_in[19];
  const float* p_mng = (const float*)d_in[20];
  const float* p_mnb = (const float*)d_in[21];
  const float* p_m1w = (const float*)d_in[22];
  const float* p_m1b = (const float*)d_in[23];
  const float* p_m2w = (const float*)d_in[24];
  const float* p_m2b = (const float*)d_in[25];
  const float* p_i0g = (const float*)d_in[26];
  const float* p_i0b = (const float*)d_in[27];
  const float* p_i1w = (const float*)d_in[28];
  const float* p_i1b = (const float*)d_in[29];
  const float* p_i2w = (const float*)d_in[30];
  const float* p_i2b = (const float*)d_in[31];
  const float* p_i3g = (const float*)d_in[32];
  const float* p_i3b = (const float*)d_in[33];
  const float* p_fw  = (const float*)d_in[34];
  const float* p_fb  = (const float*)d_in[35];

  char* ws = (char*)d_ws;
  size_t off = 0;
  auto alloc = [&](size_t bytes)->char*{
    char* p = ws + off;
    off = (off + bytes + 255) & ~(size_t)255;
    return p;
  };
  short* xln   = (short*)alloc(8192ull*768*2);
  short* h1    = (short*)alloc(8192ull*768*2);
  float* x2    = (float*)alloc(8192ull*256*4);
  short* xenc  = (short*)alloc(8192ull*256*2);
  short* kxb   = (short*)alloc(8192ull*256*2);
  short* vxb   = (short*)alloc(8192ull*256*2);
  short* hvb   = (short*)alloc(32ull*2048*256*2);
  float* dots  = (float*)alloc(32ull*2048*4);
  float* aun   = (float*)alloc(32ull*2048*4);
  float* sump  = (float*)alloc(32*8*4);
  float* hvpart= (float*)alloc(32ull*8*256*4);
  float* mompart=(float*)alloc(32*8*6*4);
  short* i1wb  = (short*)alloc(768ull*768*2);
  short* i2wb  = (short*)alloc(256ull*768*2);
  short* kwb   = (short*)alloc(256ull*256*2);
  short* vwb   = (short*)alloc(256ull*256*2);
  short* f1wb  = (short*)alloc(256ull*256*2);
  short* gwp   = (short*)alloc(256ull*64*2);
  float* slots = (float*)alloc(32*256*4);
  float* qf2   = (float*)alloc(32*256*4);
  float* qbv   = (float*)alloc(32*4);
  float* spb   = (float*)alloc(32*3*4);
  float* ssbuf = (float*)alloc(32*3*4);

  auto cvt = [&](const float* s, short* dst, int n){
    k_convert<<<(n+255)/256, 256, 0, stream>>>(s, dst, n);
  };
  cvt(p_i1w, i1wb, 768*768);
  cvt(p_i2w, i2wb, 256*768);
  cvt(p_Kw,  kwb,  256*256);
  cvt(p_Vw,  vwb,  256*256);
  cvt(p_f1w, f1wb, 256*256);
  k_prep_gwp<<<64,256,0,stream>>>(p_gw, p_gb, gwp);
  k_init<<<32,256,0,stream>>>(p_slotsp, p_Sp0, p_Ss0, slots, spb, ssbuf,
                              p_ng, p_nb, p_Qw, p_f2w, p_f2b, qf2, qbv);

  k_ln768<<<8192,256,0,stream>>>(p_inputs, p_i0g, p_i0b, xln);
  k_gemm<<<dim3(128,6),256,0,stream>>>(xln, i1wb, p_i1b, h1, 768, 768, 1|2|4);
  k_gemm<<<dim3(128,2),256,0,stream>>>(h1, i2wb, p_i2b, x2, 256, 768, 1);
  k_ln256<<<8192,256,0,stream>>>(x2, p_i3g, p_i3b, xenc);
  k_gemm<<<dim3(128,2),256,0,stream>>>(xenc, kwb, nullptr, kxb, 256, 256, 4);
  k_gemm<<<dim3(128,2),256,0,stream>>>(xenc, vwb, nullptr, vxb, 256, 256, 4);

  float* outf = (float*)d_out;
  for (int t=0;t<4;t++){
    k_isa_a<<<dim3(32,32),256,0,stream>>>(p_coords, spb, ssbuf, gwp, kxb, vxb, f1wb, p_f1b, qf2, qbv, dots, hvb, (t<3)?2:1);
    if (t < 3){
      k_c1<<<dim3(8,32),256,0,stream>>>(dots, hvb, p_coords, hvpart, mompart, sump);
      k_c2<<<32,256,0,stream>>>(hvpart, mompart, sump, p_f2w, p_f2b, spb, ssbuf,
                                p_wih, p_whh, p_bih, p_bhh, p_mng, p_mnb,
                                p_m1w, p_m1b, p_m2w, p_m2b, slots,
                                p_ng, p_nb, p_Qw, qf2, qbv);
    } else {
      k_softmax<<<32,256,0,stream>>>(dots, aun, sump);
      k_attn_out<<<256,256,0,stream>>>(aun, sump, outf + 8192);
    }
  }
  k_final<<<32,256,0,stream>>>(slots, p_fw, p_fb, outf);
}

// Round 10
// 843.676 us; speedup vs baseline: 1.7636x; 1.5835x over previous
//
#include <hip/hip_runtime.h>
#include <math.h>

#define DEVI __device__ __forceinline__

typedef __attribute__((ext_vector_type(8))) short short8;
typedef __attribute__((ext_vector_type(4))) float f32x4;

DEVI float bf2f(short u){ unsigned v = ((unsigned)(unsigned short)u) << 16; return __builtin_bit_cast(float, v); }
DEVI short f2bs(float f){
  unsigned x = __builtin_bit_cast(unsigned, f);
  unsigned r = (x + 0x7fffu + ((x >> 16) & 1u)) >> 16;
  return (short)(unsigned short)r;
}
DEVI float clampf(float x, float lo, float hi){ return fminf(fmaxf(x, lo), hi); }
DEVI float n2nf(float x){
  if (x != x) return 0.f;
  if (x == INFINITY) return 1.f;
  if (x == -INFINITY) return -1.f;
  return x;
}
DEVI float sigmoidf(float x){ return 1.f/(1.f+expf(-x)); }
DEVI f32x4 mfma16(short8 a, short8 b, f32x4 c){ return __builtin_amdgcn_mfma_f32_16x16x32_bf16(a,b,c,0,0,0); }

DEVI float blkSum(float v, float* s4, int tid){
  #pragma unroll
  for (int o=32;o;o>>=1) v += __shfl_xor(v,o);
  __syncthreads();
  if ((tid&63)==0) s4[tid>>6] = v;
  __syncthreads();
  return s4[0]+s4[1]+s4[2]+s4[3];
}

// fourier feature value for padded column c (0..63), branchless on arrays
DEVI float ffval(int c, float r0, float r1, float r2){
  if (c >= 40) return 0.f;
  if (c == 39) return 1.f;
  if (c < 3) return (c==0)?r0:((c==1)?r1:r2);
  int q = c-3, i = q/12, j = (q%12)>>1;
  float ri = (i==0)?r0:((i==1)?r1:r2);
  float ang = ri * (6.283185307179586f * (float)(1u<<j));
  return (q&1) ? __cosf(ang) : __sinf(ang);
}

// sn=LN(sl); q=sn@Qw^T; qf2=q@f2w; qbv=q.f2b
DEVI void qprep_body(float sl, int bs, int t,
    const float* __restrict__ ng, const float* __restrict__ nbv, const float* __restrict__ Qw,
    const float* __restrict__ f2w, const float* __restrict__ f2b,
    float* __restrict__ qf2, float* __restrict__ qbv,
    float* sn, float* q, float* s4){
  float m = blkSum(sl, s4, t)*(1.f/256.f);
  float d = sl - m;
  float var = blkSum(d*d, s4, t)*(1.f/256.f);
  sn[t] = d*(1.f/sqrtf(var+1e-5f))*ng[t] + nbv[t];
  __syncthreads();
  {
    const float4* qr = (const float4*)(Qw + (size_t)t*256);
    float s = 0.f;
    for (int d4=0; d4<64; ++d4){
      float4 w4 = qr[d4];
      s += sn[d4*4+0]*w4.x + sn[d4*4+1]*w4.y + sn[d4*4+2]*w4.z + sn[d4*4+3]*w4.w;
    }
    q[t] = s;
  }
  __syncthreads();
  {
    float s = 0.f;
    for (int o=0;o<256;o++) s += q[o]*f2w[(size_t)o*256 + t];
    qf2[bs*256+t] = s;
  }
  float tot = blkSum(q[t]*f2b[t], s4, t);
  if (t==0) qbv[bs] = tot;
}

// ---------------- pack kernels: W[N x KT] fp32 -> fragment-major bf16 [frag][lane][8] ----------------
__global__ void k_pack_w(const float* __restrict__ W, short* __restrict__ out, int KT, int total){
  int o = blockIdx.x*256 + threadIdx.x;
  if (o >= total) return;
  int l = o & 63;
  int frag = o >> 6;
  int KTt = KT >> 5;
  int ci = frag / KTt, kk = frag - ci*KTt;
  int col = ci*16 + (l & 15);
  int k0 = kk*32 + (l >> 4)*8;
  const float* src = W + (size_t)col*KT + k0;
  short8 v;
  #pragma unroll
  for (int e=0;e<8;e++) v[e] = f2bs(src[e]);
  *(short8*)(out + (size_t)o*8) = v;
}

__global__ void k_pack_gw(const float* __restrict__ gw, const float* __restrict__ gb, short* __restrict__ out){
  int o = blockIdx.x*256 + threadIdx.x;   // 2048 lane-slots (256 x 64 / 8)
  int l = o & 63;
  int frag = o >> 6;                      // ci*2 + kk
  int ci = frag >> 1, kk = frag & 1;
  int col = ci*16 + (l&15);
  int k0 = kk*32 + (l>>4)*8;
  short8 v;
  #pragma unroll
  for (int e=0;e<8;e++){
    int c = k0 + e;
    float x = (c < 39) ? gw[col*39 + c] : (c == 39 ? gb[col] : 0.f);
    v[e] = f2bs(x);
  }
  *(short8*)(out + (size_t)o*8) = v;
}

__global__ __launch_bounds__(256) void k_init(const float* __restrict__ slots_p, const float* __restrict__ Sp0,
                       const float* __restrict__ Ss0,
                       float* __restrict__ slots, float* __restrict__ sp, float* __restrict__ ssb,
                       const float* __restrict__ ng, const float* __restrict__ nbv, const float* __restrict__ Qw,
                       const float* __restrict__ f2w, const float* __restrict__ f2b,
                       float* __restrict__ qf2, float* __restrict__ qbv){
  int bs = blockIdx.x, t = threadIdx.x, s = bs & 7;
  __shared__ float sn[256], q[256], s4[4];
  float sl = slots_p[s*256+t];
  slots[bs*256+t] = sl;
  if (t < 3){ sp[bs*3+t] = Sp0[s*3+t]; ssb[bs*3+t] = Ss0[s*3+t]; }
  qprep_body(sl, bs, t, ng, nbv, Qw, f2w, f2b, qf2, qbv, sn, q, s4);
}

__global__ __launch_bounds__(256) void k_ln768(const float* __restrict__ in, const float* __restrict__ g,
                                               const float* __restrict__ bt, short* __restrict__ out){
  int r = blockIdx.x, t = threadIdx.x;
  __shared__ float s4[4];
  const float* row = in + (size_t)r*768;
  float x0=row[t], x1=row[256+t], x2=row[512+t];
  float m = blkSum(x0+x1+x2, s4, t) * (1.f/768.f);
  float d0=x0-m, d1=x1-m, d2=x2-m;
  float var = blkSum(d0*d0+d1*d1+d2*d2, s4, t) * (1.f/768.f);
  float rstd = 1.f/sqrtf(var + 1e-5f);
  short* orow = out + (size_t)r*768;
  orow[t]     = f2bs(d0*rstd*g[t]     + bt[t]);
  orow[256+t] = f2bs(d1*rstd*g[256+t] + bt[256+t]);
  orow[512+t] = f2bs(d2*rstd*g[512+t] + bt[512+t]);
}

__global__ __launch_bounds__(256) void k_ln256(const float* __restrict__ in, const float* __restrict__ g,
                                               const float* __restrict__ bt, short* __restrict__ out){
  int r = blockIdx.x, t = threadIdx.x;
  __shared__ float s4[4];
  float x = in[(size_t)r*256 + t];
  float m = blkSum(x, s4, t) * (1.f/256.f);
  float d = x - m;
  float var = blkSum(d*d, s4, t) * (1.f/256.f);
  out[(size_t)r*256 + t] = f2bs(d*(1.f/sqrtf(var+1e-5f))*g[t] + bt[t]);
}

// ---------------- generic MFMA GEMM, B packed fragment-major ----------------
// flags: 1=bias, 2=relu, 4=bf16out
__global__ __launch_bounds__(256) void k_gemm(const short* __restrict__ A, const short* __restrict__ Wp,
                                              const float* __restrict__ bias, void* __restrict__ outp,
                                              int ldo, int KT, int flags){
  const int w = threadIdx.x>>6, l = threadIdx.x&63, l15 = l&15, l4 = l>>4;
  const int row0 = blockIdx.x*64 + w*16;
  const int col0 = blockIdx.y*128;
  const int KTt = KT >> 5;
  f32x4 acc[8];
  #pragma unroll
  for (int i=0;i<8;i++) acc[i] = (f32x4)(0.f);
  const short* Ap = A + (size_t)(row0+l15)*KT + l4*8;
  #pragma unroll 2
  for (int kk=0; kk<KT/32; ++kk){
    short8 af = *(const short8*)(Ap + kk*32);
    #pragma unroll
    for (int ci=0; ci<8; ++ci){
      const short* bp = Wp + (((size_t)(blockIdx.y*8+ci)*KTt + kk)*64 + l)*8;
      acc[ci] = mfma16(af, *(const short8*)bp, acc[ci]);
    }
  }
  #pragma unroll
  for (int ci=0; ci<8; ++ci){
    int col = col0 + ci*16 + l15;
    float bv = (flags&1) ? bias[col] : 0.f;
    #pragma unroll
    for (int j=0;j<4;j++){
      int row = row0 + l4*4 + j;
      float v = acc[ci][j] + bv;
      if (flags&2) v = fmaxf(v, 0.f);
      if (flags&4) ((short*)outp)[(size_t)row*ldo + col] = f2bs(v);
      else         ((float*)outp)[(size_t)row*ldo + col] = v;
    }
  }
}

// ---------------- the big fused kernel ----------------
// grid (N/64, B*S, npass), 256 threads. blockIdx.z: 0=K pass (dots), 1=V pass (hv).
__global__ __launch_bounds__(256, 4) void k_isa_a(
    const float* __restrict__ coords, const float* __restrict__ sp, const float* __restrict__ ssb,
    const short* __restrict__ gwp, const short* __restrict__ kx, const short* __restrict__ vx,
    const short* __restrict__ f1wp, const float* __restrict__ f1b,
    const float* __restrict__ qf2, const float* __restrict__ qbv,
    float* __restrict__ dots, short* __restrict__ hv){
  __shared__ __align__(16) short abuf[64*256];
  __shared__ float sf1b[256];
  __shared__ float sqf2[256];
  __shared__ float smisc[8];
  const int tid = threadIdx.x;
  const int bs = blockIdx.y;
  const int b  = bs >> 3;
  const int n0 = blockIdx.x * 64;
  const int pass = blockIdx.z;

  sf1b[tid] = f1b[tid];
  sqf2[tid] = qf2[bs*256 + tid];
  if (tid < 3){
    smisc[tid] = sp[bs*3+tid];
    float sv = ssb[bs*3+tid];
    float sa = clampf(sv, 0.3f, 5.f) + 0.1f;
    smisc[4+tid] = 1.f/(sa*5.f + 1e-4f);
  }
  if (tid == 7) smisc[7] = qbv[bs];
  __syncthreads();

  const int w = tid>>6, l = tid&63, l15 = l&15, l4 = l>>4;
  const int ar = w*16 + l15;           // A-row this lane owns

  // ---- fourier-feature A-fragments in registers (row ar, k = l4*8.. and 32+l4*8..) ----
  short8 ag0, ag1;
  {
    const float* cp0 = coords + ((size_t)(b*2048 + n0 + ar))*3;
    float r0 = clampf((cp0[0] - smisc[0]) * smisc[4], -3.f, 3.f);
    float r1 = clampf((cp0[1] - smisc[1]) * smisc[5], -3.f, 3.f);
    float r2 = clampf((cp0[2] - smisc[2]) * smisc[6], -3.f, 3.f);
    #pragma unroll
    for (int e=0;e<8;e++) ag0[e] = f2bs(ffval(l4*8+e,      r0,r1,r2));
    #pragma unroll
    for (int e=0;e<8;e++) ag1[e] = f2bs(ffval(32+l4*8+e,   r0,r1,r2));
  }

  // ---- gr GEMM (K=64), packed gw, write bf16 to abuf (swizzled, wave-own rows) ----
  #pragma unroll 2
  for (int cc=0; cc<8; ++cc){
    int f0 = (2*cc)*2, f1 = (2*cc+1)*2;
    f32x4 a0 = (f32x4)(0.f), a1 = (f32x4)(0.f);
    a0 = mfma16(ag0, *(const short8*)(gwp + ((size_t)(f0  )*64 + l)*8), a0);
    a0 = mfma16(ag1, *(const short8*)(gwp + ((size_t)(f0+1)*64 + l)*8), a0);
    a1 = mfma16(ag0, *(const short8*)(gwp + ((size_t)(f1  )*64 + l)*8), a1);
    a1 = mfma16(ag1, *(const short8*)(gwp + ((size_t)(f1+1)*64 + l)*8), a1);
    int c0 = (2*cc)*16 + l15, c1 = (2*cc+1)*16 + l15;
    #pragma unroll
    for (int j=0;j<4;j++){
      int row = w*16 + l4*4 + j;
      abuf[row*256 + (((c0>>3)^(row&7))<<3) + (c0&7)] = f2bs(a0[j]);
      abuf[row*256 + (((c1>>3)^(row&7))<<3) + (c1&7)] = f2bs(a1[j]);
    }
  }
  __syncthreads();
  // ---- abuf += Kx|Vx  (vectorized short8 RMW) ----
  {
    const short* srcb = pass ? vx : kx;
    #pragma unroll
    for (int i=0;i<8;i++){
      int gid = tid + i*256;
      int row = gid>>5, cg = gid&31;
      short8 sv = *(const short8*)(srcb + ((size_t)(b*2048 + n0 + row))*256 + cg*8);
      short* ap = &abuf[row*256 + ((cg^(row&7))<<3)];
      short8 av = *(const short8*)ap;
      short8 ov;
      #pragma unroll
      for (int e=0;e<8;e++) ov[e] = f2bs(bf2f(av[e]) + bf2f(sv[e]));
      *(short8*)ap = ov;
    }
  }
  __syncthreads();
  // ---- f1 GEMM (K=256): A-fragments from LDS, packed B ----
  short8 af[8];
  #pragma unroll
  for (int kk=0;kk<8;kk++)
    af[kk] = *(const short8*)&abuf[ar*256 + (((kk*4+l4) ^ (ar&7))<<3)];

  if (pass == 0){
    float p0=0.f,p1=0.f,p2=0.f,p3=0.f;
    #pragma unroll 2
    for (int cc=0; cc<8; ++cc){
      int ct0 = 2*cc, ct1 = 2*cc+1;
      f32x4 a0 = (f32x4)(0.f), a1 = (f32x4)(0.f);
      #pragma unroll
      for (int kk=0;kk<8;kk++){
        a0 = mfma16(af[kk], *(const short8*)(f1wp + (((size_t)ct0*8 + kk)*64 + l)*8), a0);
        a1 = mfma16(af[kk], *(const short8*)(f1wp + (((size_t)ct1*8 + kk)*64 + l)*8), a1);
      }
      int c0 = ct0*16 + l15, c1 = ct1*16 + l15;
      float q0=sqf2[c0], b0=sf1b[c0], q1=sqf2[c1], b1=sf1b[c1];
      p0 += fmaxf(a0[0]+b0,0.f)*q0 + fmaxf(a1[0]+b1,0.f)*q1;
      p1 += fmaxf(a0[1]+b0,0.f)*q0 + fmaxf(a1[1]+b1,0.f)*q1;
      p2 += fmaxf(a0[2]+b0,0.f)*q0 + fmaxf(a1[2]+b1,0.f)*q1;
      p3 += fmaxf(a0[3]+b0,0.f)*q0 + fmaxf(a1[3]+b1,0.f)*q1;
    }
    #pragma unroll
    for (int o=8;o;o>>=1){
      p0 += __shfl_xor(p0,o); p1 += __shfl_xor(p1,o);
      p2 += __shfl_xor(p2,o); p3 += __shfl_xor(p3,o);
    }
    if (l15 == 0){
      float pj[4] = {p0,p1,p2,p3};
      #pragma unroll
      for (int j=0;j<4;j++){
        int row = w*16 + l4*4 + j;
        float dd = clampf((pj[j] + smisc[7]) * 0.0625f, -30.f, 30.f);
        dots[(size_t)bs*2048 + n0 + row] = dd;
      }
    }
  } else {
    #pragma unroll 2
    for (int cc=0; cc<8; ++cc){
      int ct0 = 2*cc, ct1 = 2*cc+1;
      f32x4 a0 = (f32x4)(0.f), a1 = (f32x4)(0.f);
      #pragma unroll
      for (int kk=0;kk<8;kk++){
        a0 = mfma16(af[kk], *(const short8*)(f1wp + (((size_t)ct0*8 + kk)*64 + l)*8), a0);
        a1 = mfma16(af[kk], *(const short8*)(f1wp + (((size_t)ct1*8 + kk)*64 + l)*8), a1);
      }
      int c0 = ct0*16 + l15, c1 = ct1*16 + l15;
      float b0=sf1b[c0], b1=sf1b[c1];
      #pragma unroll
      for (int j=0;j<4;j++){
        int row = w*16 + l4*4 + j;
        abuf[row*256 + (((c0>>3)^(row&7))<<3) + (c0&7)] = f2bs(fmaxf(a0[j]+b0,0.f));
        abuf[row*256 + (((c1>>3)^(row&7))<<3) + (c1&7)] = f2bs(fmaxf(a1[j]+b1,0.f));
      }
    }
    __syncthreads();
    #pragma unroll
    for (int i=0;i<8;i++){
      int gid = tid + i*256;
      int row = gid>>5, cg = gid&31;
      short8 av = *(const short8*)&abuf[row*256 + ((cg^(row&7))<<3)];
      *(short8*)(hv + ((size_t)(bs*2048 + n0 + row))*256 + cg*8) = av;
    }
  }
}

// ---------------- softmax (t=3 only, feeds attn output) ----------------
__global__ __launch_bounds__(256) void k_softmax(const float* __restrict__ dots, float* __restrict__ aun,
                                                 float* __restrict__ sump){
  int blk = blockIdx.x;
  int b = blk >> 3, chunk = blk & 7;
  int n = chunk*256 + threadIdx.x;
  float d[8];
  #pragma unroll
  for (int s=0;s<8;s++) d[s] = dots[(size_t)(b*8+s)*2048 + n];
  float m = d[0];
  #pragma unroll
  for (int s=1;s<8;s++) m = fmaxf(m, d[s]);
  float e[8]; float sum = 0.f;
  #pragma unroll
  for (int s=0;s<8;s++){ e[s] = expf(d[s]-m); sum += e[s]; }
  float inv = 1.f/sum;
  __shared__ float red[4][8];
  int wv = threadIdx.x>>6, ln = threadIdx.x&63;
  #pragma unroll
  for (int s=0;s<8;s++){
    float a = e[s]*inv + 1e-8f;
    aun[(size_t)(b*8+s)*2048 + n] = a;
    float v = a;
    #pragma unroll
    for (int o=32;o;o>>=1) v += __shfl_xor(v,o);
    if (ln == 0) red[wv][s] = v;
  }
  __syncthreads();
  if (threadIdx.x < 8){
    int s = threadIdx.x;
    sump[(b*8+s)*8 + chunk] = red[0][s]+red[1][s]+red[2][s]+red[3][s];
  }
}

// ---------------- fused softmax + weighted partial reductions (t<3) ----------------
__global__ __launch_bounds__(256) void k_c1(const float* __restrict__ dots, const short* __restrict__ hv,
    const float* __restrict__ coords, float* __restrict__ hvpart, float* __restrict__ mompart,
    float* __restrict__ sump){
  int chunk = blockIdx.x, bs = blockIdx.y, b = bs >> 3, so = bs & 7;
  int t = threadIdx.x;
  int nb = chunk*256;
  __shared__ float wsm[256];
  {
    float d[8];
    #pragma unroll
    for (int s=0;s<8;s++) d[s] = dots[(size_t)(b*8+s)*2048 + nb + t];
    float m = d[0];
    #pragma unroll
    for (int s=1;s<8;s++) m = fmaxf(m, d[s]);
    float sum = 0.f; float eo = 0.f;
    #pragma unroll
    for (int s=0;s<8;s++){ float e = expf(d[s]-m); sum += e; if (s==so) eo = e; }
    wsm[t] = eo/sum + 1e-8f;
  }
  __syncthreads();
  float acc = 0.f;
  const short* hp = hv + ((size_t)bs*2048 + nb)*256 + t;
  #pragma unroll 4
  for (int n=0;n<256;n++) acc += wsm[n]*bf2f(hp[(size_t)n*256]);
  hvpart[(size_t)(bs*8+chunk)*256 + t] = acc;
  float wv = wsm[t];
  const float* cp = coords + ((size_t)(b*2048) + nb + t)*3;
  float c0=cp[0], c1=cp[1], c2=cp[2];
  float mv[7] = {wv*c0, wv*c1, wv*c2, wv*c0*c0, wv*c1*c1, wv*c2*c2, wv};
  __shared__ float red[4][7];
  int wvx = t>>6, ln = t&63;
  #pragma unroll
  for (int i=0;i<7;i++){
    float v = mv[i];
    #pragma unroll
    for (int o=32;o;o>>=1) v += __shfl_xor(v,o);
    if (ln==0) red[wvx][i] = v;
  }
  __syncthreads();
  if (t<7){
    float r = red[0][t]+red[1][t]+red[2][t]+red[3][t];
    if (t<6) mompart[(bs*8+chunk)*6 + t] = r;
    else     sump[bs*8 + chunk] = r;
  }
}

// ---------------- final per-(b,s): updates, S_p, S_s, GRU, LN, MLP, then qprep for next iter ----------------
__global__ __launch_bounds__(256) void k_c2(
    const float* __restrict__ hvpart, const float* __restrict__ mompart, const float* __restrict__ sump,
    const float* __restrict__ f2w, const float* __restrict__ f2b,
    float* __restrict__ sp, float* __restrict__ ssb,
    const float* __restrict__ wih, const float* __restrict__ whh,
    const float* __restrict__ bih, const float* __restrict__ bhh,
    const float* __restrict__ m_ng, const float* __restrict__ m_nb,
    const float* __restrict__ m1w, const float* __restrict__ m1b,
    const float* __restrict__ m2w, const float* __restrict__ m2b,
    float* __restrict__ slots,
    const float* __restrict__ ng, const float* __restrict__ nbv, const float* __restrict__ Qw,
    float* __restrict__ qf2, float* __restrict__ qbv){
  int bs = blockIdx.x, t = threadIdx.x;
  __shared__ float hs[256], u[256], spv[256], hln[256], r1[1024];
  __shared__ float sc[8], s4[4];
  {
    float a=0.f;
    #pragma unroll
    for (int c=0;c<8;c++) a += hvpart[(size_t)(bs*8+c)*256 + t];
    hs[t] = a;
  }
  spv[t] = slots[bs*256+t];
  if (t == 0){
    float A0=0.f;
    for (int c=0;c<8;c++) A0 += sump[bs*8+c];
    sc[0]=A0; sc[1]=A0+1e-8f;
  }
  if (t < 6){
    float mm=0.f;
    for (int c=0;c<8;c++) mm += mompart[(bs*8+c)*6 + t];
    sc[2+t] = mm;
  }
  __syncthreads();
  float A0 = sc[0], denom = sc[1];
  if (t < 3){
    float A1 = sc[2+t], A2 = sc[5+t];
    float p = A1/denom;
    float var = (A2 - 2.f*p*A1 + p*p*A0)/denom + 1e-6f;
    float sv = clampf(sqrtf(var), 0.2f, 5.f);
    sp[bs*3+t] = p; ssb[bs*3+t] = sv;
  }
  {
    float dd = 0.f;
    const float4* fr = (const float4*)(f2w + (size_t)t*256);
    for (int h4=0; h4<64; ++h4){
      float4 w4 = fr[h4];
      dd += hs[h4*4+0]*w4.x + hs[h4*4+1]*w4.y + hs[h4*4+2]*w4.z + hs[h4*4+3]*w4.w;
    }
    u[t] = n2nf((dd + A0*f2b[t])/denom);
  }
  __syncthreads();
  float gi[3], gh[3];
  #pragma unroll 1
  for (int part=0; part<3; ++part){
    int o = part*256 + t;
    const float4* wr = (const float4*)(wih + (size_t)o*256);
    const float4* hr = (const float4*)(whh + (size_t)o*256);
    float si = bih[o], sh = bhh[o];
    for (int d4=0; d4<64; ++d4){
      float4 a4 = wr[d4], b4 = hr[d4];
      si += u[d4*4+0]*a4.x + u[d4*4+1]*a4.y + u[d4*4+2]*a4.z + u[d4*4+3]*a4.w;
      sh += spv[d4*4+0]*b4.x + spv[d4*4+1]*b4.y + spv[d4*4+2]*b4.z + spv[d4*4+3]*b4.w;
    }
    gi[part]=si; gh[part]=sh;
  }
  float rg = sigmoidf(gi[0]+gh[0]);
  float zg = sigmoidf(gi[1]+gh[1]);
  float nn = tanhf(gi[2] + rg*gh[2]);
  float hnew = (1.f-zg)*nn + zg*spv[t];
  float m = blkSum(hnew, s4, t)*(1.f/256.f);
  float dv = hnew - m;
  float var = blkSum(dv*dv, s4, t)*(1.f/256.f);
  hln[t] = dv*(1.f/sqrtf(var+1e-5f))*m_ng[t] + m_nb[t];
  __syncthreads();
  #pragma unroll 1
  for (int oi=0; oi<4; ++oi){
    int o = t*4 + oi;
    const float4* mr = (const float4*)(m1w + (size_t)o*256);
    float s = m1b[o];
    for (int d4=0; d4<64; ++d4){
      float4 a4 = mr[d4];
      s += hln[d4*4+0]*a4.x + hln[d4*4+1]*a4.y + hln[d4*4+2]*a4.z + hln[d4*4+3]*a4.w;
    }
    r1[o] = fmaxf(s, 0.f);
  }
  __syncthreads();
  float sl;
  {
    const float4* mr = (const float4*)(m2w + (size_t)t*1024);
    float s = m2b[t];
    for (int o4=0; o4<256; ++o4){
      float4 a4 = mr[o4];
      s += r1[o4*4+0]*a4.x + r1[o4*4+1]*a4.y + r1[o4*4+2]*a4.z + r1[o4*4+3]*a4.w;
    }
    sl = n2nf(hnew + s);
    slots[bs*256+t] = sl;
  }
  qprep_body(sl, bs, t, ng, nbv, Qw, f2w, f2b, qf2, qbv, hs, u, s4);
}

__global__ __launch_bounds__(256) void k_attn_out(const float* __restrict__ aun, const float* __restrict__ sump,
                                                  float* __restrict__ outp){
  int g = blockIdx.x*256 + threadIdx.x;
  int bs = g >> 11;
  __shared__ float dsh;
  if (threadIdx.x == 0){
    float s=0.f;
    for (int c=0;c<8;c++) s += sump[bs*8+c];
    dsh = s + 1e-8f;
  }
  __syncthreads();
  outp[g] = aun[g] / dsh;
}

__global__ __launch_bounds__(256) void k_final(const float* __restrict__ slots,
    const float* __restrict__ fw, const float* __restrict__ fb, float* __restrict__ outp){
  int bs = blockIdx.x, t = threadIdx.x;
  __shared__ float sl[256];
  sl[t] = slots[bs*256+t];
  __syncthreads();
  const float4* fr = (const float4*)(fw + (size_t)t*256);
  float s = fb[t];
  for (int d4=0; d4<64; ++d4){
    float4 w4 = fr[d4];
    s += sl[d4*4+0]*w4.x + sl[d4*4+1]*w4.y + sl[d4*4+2]*w4.z + sl[d4*4+3]*w4.w;
  }
  outp[bs*256+t] = s;
}

extern "C" void kernel_launch(void* const* d_in, const int* in_sizes, int n_in,
                              void* d_out, int out_size, void* d_ws, size_t ws_size,
                              hipStream_t stream){
  const float* p_inputs = (const float*)d_in[0];
  const float* p_coords = (const float*)d_in[1];
  const float* p_slotsp = (const float*)d_in[2];
  const float* p_Ss0 = (const float*)d_in[3];
  const float* p_Sp0 = (const float*)d_in[4];
  const float* p_Qw  = (const float*)d_in[5];
  const float* p_Kw  = (const float*)d_in[6];
  const float* p_Vw  = (const float*)d_in[7];
  const float* p_gw  = (const float*)d_in[8];
  const float* p_gb  = (const float*)d_in[9];
  const float* p_f1w = (const float*)d_in[10];
  const float* p_f1b = (const float*)d_in[11];
  const float* p_f2w = (const float*)d_in[12];
  const float* p_f2b = (const float*)d_in[13];
  const float* p_ng  = (const float*)d_in[14];
  const float* p_nb  = (const float*)d_in[15];
  const float* p_wih = (const float*)d_in[16];
  const float* p_whh = (const float*)d_in[17];
  const float* p_bih = (const float*)d_in[18];
  const float* p_bhh = (const float*)d_in[19];
  const float* p_mng = (const float*)d_in[20];
  const float* p_mnb = (const float*)d_in[21];
  const float* p_m1w = (const float*)d_in[22];
  const float* p_m1b = (const float*)d_in[23];
  const float* p_m2w = (const float*)d_in[24];
  const float* p_m2b = (const float*)d_in[25];
  const float* p_i0g = (const float*)d_in[26];
  const float* p_i0b = (const float*)d_in[27];
  const float* p_i1w = (const float*)d_in[28];
  const float* p_i1b = (const float*)d_in[29];
  const float* p_i2w = (const float*)d_in[30];
  const float* p_i2b = (const float*)d_in[31];
  const float* p_i3g = (const float*)d_in[32];
  const float* p_i3b = (const float*)d_in[33];
  const float* p_fw  = (const float*)d_in[34];
  const float* p_fb  = (const float*)d_in[35];

  char* ws = (char*)d_ws;
  size_t off = 0;
  auto alloc = [&](size_t bytes)->char*{
    char* p = ws + off;
    off = (off + bytes + 255) & ~(size_t)255;
    return p;
  };
  short* xln   = (short*)alloc(8192ull*768*2);
  short* h1    = (short*)alloc(8192ull*768*2);
  float* x2    = (float*)alloc(8192ull*256*4);
  short* xenc  = (short*)alloc(8192ull*256*2);
  short* kxb   = (short*)alloc(8192ull*256*2);
  short* vxb   = (short*)alloc(8192ull*256*2);
  short* hvb   = (short*)alloc(32ull*2048*256*2);
  float* dots  = (float*)alloc(32ull*2048*4);
  float* aun   = (float*)alloc(32ull*2048*4);
  float* sump  = (float*)alloc(32*8*4);
  float* hvpart= (float*)alloc(32ull*8*256*4);
  float* mompart=(float*)alloc(32*8*6*4);
  short* i1wp  = (short*)alloc(768ull*768*2);
  short* i2wp  = (short*)alloc(256ull*768*2);
  short* kwp   = (short*)alloc(256ull*256*2);
  short* vwp   = (short*)alloc(256ull*256*2);
  short* f1wp  = (short*)alloc(256ull*256*2);
  short* gwp   = (short*)alloc(256ull*64*2);
  float* slots = (float*)alloc(32*256*4);
  float* qf2   = (float*)alloc(32*256*4);
  float* qbv   = (float*)alloc(32*4);
  float* spb   = (float*)alloc(32*3*4);
  float* ssbuf = (float*)alloc(32*3*4);

  k_pack_w<<<(768*768/8+255)/256,256,0,stream>>>(p_i1w, i1wp, 768, 768*768/8);
  k_pack_w<<<(256*768/8+255)/256,256,0,stream>>>(p_i2w, i2wp, 768, 256*768/8);
  k_pack_w<<<(256*256/8+255)/256,256,0,stream>>>(p_Kw,  kwp,  256, 256*256/8);
  k_pack_w<<<(256*256/8+255)/256,256,0,stream>>>(p_Vw,  vwp,  256, 256*256/8);
  k_pack_w<<<(256*256/8+255)/256,256,0,stream>>>(p_f1w, f1wp, 256, 256*256/8);
  k_pack_gw<<<8,256,0,stream>>>(p_gw, p_gb, gwp);
  k_init<<<32,256,0,stream>>>(p_slotsp, p_Sp0, p_Ss0, slots, spb, ssbuf,
                              p_ng, p_nb, p_Qw, p_f2w, p_f2b, qf2, qbv);

  k_ln768<<<8192,256,0,stream>>>(p_inputs, p_i0g, p_i0b, xln);
  k_gemm<<<dim3(128,6),256,0,stream>>>(xln, i1wp, p_i1b, h1, 768, 768, 1|2|4);
  k_gemm<<<dim3(128,2),256,0,stream>>>(h1, i2wp, p_i2b, x2, 256, 768, 1);
  k_ln256<<<8192,256,0,stream>>>(x2, p_i3g, p_i3b, xenc);
  k_gemm<<<dim3(128,2),256,0,stream>>>(xenc, kwp, nullptr, kxb, 256, 256, 4);
  k_gemm<<<dim3(128,2),256,0,stream>>>(xenc, vwp, nullptr, vxb, 256, 256, 4);

  float* outf = (float*)d_out;
  for (int t=0;t<4;t++){
    k_isa_a<<<dim3(32,32,(t<3)?2:1),256,0,stream>>>(p_coords, spb, ssbuf, gwp, kxb, vxb, f1wp, p_f1b, qf2, qbv, dots, hvb);
    if (t < 3){
      k_c1<<<dim3(8,32),256,0,stream>>>(dots, hvb, p_coords, hvpart, mompart, sump);
      k_c2<<<32,256,0,stream>>>(hvpart, mompart, sump, p_f2w, p_f2b, spb, ssbuf,
                                p_wih, p_whh, p_bih, p_bhh, p_mng, p_mnb,
                                p_m1w, p_m1b, p_m2w, p_m2b, slots,
                                p_ng, p_nb, p_Qw, qf2, qbv);
    } else {
      k_softmax<<<32,256,0,stream>>>(dots, aun, sump);
      k_attn_out<<<256,256,0,stream>>>(aun, sump, outf + 8192);
    }
  }
  k_final<<<32,256,0,stream>>>(slots, p_fw, p_fb, outf);
}

// Round 26
// 700.249 us; speedup vs baseline: 2.1248x; 1.2048x over previous
//
#include <hip/hip_runtime.h>
#include <math.h>

#define DEVI __device__ __forceinline__

typedef __attribute__((ext_vector_type(8))) short short8;
typedef __attribute__((ext_vector_type(4))) float f32x4;

DEVI float bf2f(short u){ unsigned v = ((unsigned)(unsigned short)u) << 16; return __builtin_bit_cast(float, v); }
DEVI short f2bs(float f){
  unsigned x = __builtin_bit_cast(unsigned, f);
  unsigned r = (x + 0x7fffu + ((x >> 16) & 1u)) >> 16;
  return (short)(unsigned short)r;
}
DEVI float clampf(float x, float lo, float hi){ return fminf(fmaxf(x, lo), hi); }
DEVI float n2nf(float x){
  if (x != x) return 0.f;
  if (x == INFINITY) return 1.f;
  if (x == -INFINITY) return -1.f;
  return x;
}
DEVI float sigmoidf(float x){ return 1.f/(1.f+expf(-x)); }
DEVI f32x4 mfma16(short8 a, short8 b, f32x4 c){ return __builtin_amdgcn_mfma_f32_16x16x32_bf16(a,b,c,0,0,0); }

DEVI float blkSum(float v, float* s4, int tid){
  #pragma unroll
  for (int o=32;o;o>>=1) v += __shfl_xor(v,o);
  __syncthreads();
  if ((tid&63)==0) s4[tid>>6] = v;
  __syncthreads();
  return s4[0]+s4[1]+s4[2]+s4[3];
}

DEVI float ffval(int c, float r0, float r1, float r2){
  if (c >= 40) return 0.f;
  if (c == 39) return 1.f;
  if (c < 3) return (c==0)?r0:((c==1)?r1:r2);
  int q = c-3, i = q/12, j = (q%12)>>1;
  float ri = (i==0)?r0:((i==1)?r1:r2);
  float ang = ri * (6.283185307179586f * (float)(1u<<j));
  return (q&1) ? __cosf(ang) : __sinf(ang);
}

// sn=LN(sl); q=sn@Qw^T; qf2=q@f2w (f2wT rows); qbv=q.f2b
DEVI void qprep_body(float sl, int bs, int t,
    const float* __restrict__ ng, const float* __restrict__ nbv, const float* __restrict__ Qw,
    const float* __restrict__ f2wT, const float* __restrict__ f2b,
    float* __restrict__ qf2, float* __restrict__ qbv,
    float* sn, float* q, float* s4){
  float m = blkSum(sl, s4, t)*(1.f/256.f);
  float d = sl - m;
  float var = blkSum(d*d, s4, t)*(1.f/256.f);
  sn[t] = d*(1.f/sqrtf(var+1e-5f))*ng[t] + nbv[t];
  __syncthreads();
  {
    const float4* qr = (const float4*)(Qw + (size_t)t*256);
    float s = 0.f;
    for (int d4=0; d4<64; ++d4){
      float4 w4 = qr[d4];
      s += sn[d4*4+0]*w4.x + sn[d4*4+1]*w4.y + sn[d4*4+2]*w4.z + sn[d4*4+3]*w4.w;
    }
    q[t] = s;
  }
  __syncthreads();
  {
    const float4* fr = (const float4*)(f2wT + (size_t)t*256);
    float s = 0.f;
    for (int d4=0; d4<64; ++d4){
      float4 w4 = fr[d4];
      s += q[d4*4+0]*w4.x + q[d4*4+1]*w4.y + q[d4*4+2]*w4.z + q[d4*4+3]*w4.w;
    }
    qf2[bs*256+t] = s;
  }
  float tot = blkSum(q[t]*f2b[t], s4, t);
  if (t==0) qbv[bs] = tot;
}

// ---------------- utility kernels ----------------
__global__ void k_convert(const float* __restrict__ s, short* __restrict__ d, int n){
  int i = blockIdx.x*256 + threadIdx.x;
  if (i < n) d[i] = f2bs(s[i]);
}

__global__ void k_transpose256(const float* __restrict__ in, float* __restrict__ out){
  int c = blockIdx.x, r = threadIdx.x;
  out[(size_t)c*256 + r] = in[(size_t)r*256 + c];
}

__global__ void k_pack_w(const float* __restrict__ W, short* __restrict__ out, int KT, int total){
  int o = blockIdx.x*256 + threadIdx.x;
  if (o >= total) return;
  int l = o & 63;
  int frag = o >> 6;
  int KTt = KT >> 5;
  int ci = frag / KTt, kk = frag - ci*KTt;
  int col = ci*16 + (l & 15);
  int k0 = kk*32 + (l >> 4)*8;
  const float* src = W + (size_t)col*KT + k0;
  short8 v;
  #pragma unroll
  for (int e=0;e<8;e++) v[e] = f2bs(src[e]);
  *(short8*)(out + (size_t)o*8) = v;
}

__global__ void k_pack_gw(const float* __restrict__ gw, const float* __restrict__ gb, short* __restrict__ out){
  int o = blockIdx.x*256 + threadIdx.x;
  int l = o & 63;
  int frag = o >> 6;
  int ci = frag >> 1, kk = frag & 1;
  int col = ci*16 + (l&15);
  int k0 = kk*32 + (l>>4)*8;
  short8 v;
  #pragma unroll
  for (int e=0;e<8;e++){
    int c = k0 + e;
    float x = (c < 39) ? gw[col*39 + c] : (c == 39 ? gb[col] : 0.f);
    v[e] = f2bs(x);
  }
  *(short8*)(out + (size_t)o*8) = v;
}

__global__ __launch_bounds__(256) void k_init(const float* __restrict__ slots_p, const float* __restrict__ Sp0,
                       const float* __restrict__ Ss0,
                       float* __restrict__ slots, float* __restrict__ sp, float* __restrict__ ssb,
                       const float* __restrict__ ng, const float* __restrict__ nbv, const float* __restrict__ Qw,
                       const float* __restrict__ f2wT, const float* __restrict__ f2b,
                       float* __restrict__ qf2, float* __restrict__ qbv){
  int bs = blockIdx.x, t = threadIdx.x, s = bs & 7;
  __shared__ float sn[256], q[256], s4[4];
  float sl = slots_p[s*256+t];
  slots[bs*256+t] = sl;
  if (t < 3){ sp[bs*3+t] = Sp0[s*3+t]; ssb[bs*3+t] = Ss0[s*3+t]; }
  qprep_body(sl, bs, t, ng, nbv, Qw, f2wT, f2b, qf2, qbv, sn, q, s4);
}

__global__ __launch_bounds__(256) void k_ln768(const float* __restrict__ in, const float* __restrict__ g,
                                               const float* __restrict__ bt, short* __restrict__ out){
  int r = blockIdx.x, t = threadIdx.x;
  __shared__ float s4[4];
  const float* row = in + (size_t)r*768;
  float x0=row[t], x1=row[256+t], x2=row[512+t];
  float m = blkSum(x0+x1+x2, s4, t) * (1.f/768.f);
  float d0=x0-m, d1=x1-m, d2=x2-m;
  float var = blkSum(d0*d0+d1*d1+d2*d2, s4, t) * (1.f/768.f);
  float rstd = 1.f/sqrtf(var + 1e-5f);
  short* orow = out + (size_t)r*768;
  orow[t]     = f2bs(d0*rstd*g[t]     + bt[t]);
  orow[256+t] = f2bs(d1*rstd*g[256+t] + bt[256+t]);
  orow[512+t] = f2bs(d2*rstd*g[512+t] + bt[512+t]);
}

__global__ __launch_bounds__(256) void k_ln256(const float* __restrict__ in, const float* __restrict__ g,
                                               const float* __restrict__ bt, short* __restrict__ out){
  int r = blockIdx.x, t = threadIdx.x;
  __shared__ float s4[4];
  float x = in[(size_t)r*256 + t];
  float m = blkSum(x, s4, t) * (1.f/256.f);
  float d = x - m;
  float var = blkSum(d*d, s4, t) * (1.f/256.f);
  out[(size_t)r*256 + t] = f2bs(d*(1.f/sqrtf(var+1e-5f))*g[t] + bt[t]);
}

// ---------------- generic MFMA GEMM, B packed fragment-major ----------------
// flags: 1=bias, 2=relu, 4=bf16out
__global__ __launch_bounds__(256) void k_gemm(const short* __restrict__ A, const short* __restrict__ Wp,
                                              const float* __restrict__ bias, void* __restrict__ outp,
                                              int ldo, int KT, int flags){
  const int w = threadIdx.x>>6, l = threadIdx.x&63, l15 = l&15, l4 = l>>4;
  const int row0 = blockIdx.x*64 + w*16;
  const int col0 = blockIdx.y*128;
  const int KTt = KT >> 5;
  f32x4 acc[8];
  #pragma unroll
  for (int i=0;i<8;i++) acc[i] = (f32x4)(0.f);
  const short* Ap = A + (size_t)(row0+l15)*KT + l4*8;
  #pragma unroll 2
  for (int kk=0; kk<KT/32; ++kk){
    short8 af = *(const short8*)(Ap + kk*32);
    #pragma unroll
    for (int ci=0; ci<8; ++ci){
      const short* bp = Wp + (((size_t)(blockIdx.y*8+ci)*KTt + kk)*64 + l)*8;
      acc[ci] = mfma16(af, *(const short8*)bp, acc[ci]);
    }
  }
  #pragma unroll
  for (int ci=0; ci<8; ++ci){
    int col = col0 + ci*16 + l15;
    float bv = (flags&1) ? bias[col] : 0.f;
    #pragma unroll
    for (int j=0;j<4;j++){
      int row = row0 + l4*4 + j;
      float v = acc[ci][j] + bv;
      if (flags&2) v = fmaxf(v, 0.f);
      if (flags&4) ((short*)outp)[(size_t)row*ldo + col] = f2bs(v);
      else         ((float*)outp)[(size_t)row*ldo + col] = v;
    }
  }
}

// ---------------- the big fused kernel ----------------
__global__ __launch_bounds__(256, 4) void k_isa_a(
    const float* __restrict__ coords, const float* __restrict__ sp, const float* __restrict__ ssb,
    const short* __restrict__ gwp, const short* __restrict__ kx, const short* __restrict__ vx,
    const short* __restrict__ f1wp, const float* __restrict__ f1b,
    const float* __restrict__ qf2, const float* __restrict__ qbv,
    float* __restrict__ dots, short* __restrict__ hv){
  __shared__ __align__(16) short abuf[64*256];
  __shared__ float sf1b[256];
  __shared__ float sqf2[256];
  __shared__ float smisc[8];
  const int tid = threadIdx.x;
  const int bs = blockIdx.y;
  const int b  = bs >> 3;
  const int n0 = blockIdx.x * 64;
  const int pass = blockIdx.z;

  sf1b[tid] = f1b[tid];
  sqf2[tid] = qf2[bs*256 + tid];
  if (tid < 3){
    smisc[tid] = sp[bs*3+tid];
    float sv = ssb[bs*3+tid];
    float sa = clampf(sv, 0.3f, 5.f) + 0.1f;
    smisc[4+tid] = 1.f/(sa*5.f + 1e-4f);
  }
  if (tid == 7) smisc[7] = qbv[bs];
  __syncthreads();

  const int w = tid>>6, l = tid&63, l15 = l&15, l4 = l>>4;
  const int ar = w*16 + l15;

  short8 ag0, ag1;
  {
    const float* cp0 = coords + ((size_t)(b*2048 + n0 + ar))*3;
    float r0 = clampf((cp0[0] - smisc[0]) * smisc[4], -3.f, 3.f);
    float r1 = clampf((cp0[1] - smisc[1]) * smisc[5], -3.f, 3.f);
    float r2 = clampf((cp0[2] - smisc[2]) * smisc[6], -3.f, 3.f);
    #pragma unroll
    for (int e=0;e<8;e++) ag0[e] = f2bs(ffval(l4*8+e,      r0,r1,r2));
    #pragma unroll
    for (int e=0;e<8;e++) ag1[e] = f2bs(ffval(32+l4*8+e,   r0,r1,r2));
  }

  #pragma unroll 2
  for (int cc=0; cc<8; ++cc){
    int f0 = (2*cc)*2, f1 = (2*cc+1)*2;
    f32x4 a0 = (f32x4)(0.f), a1 = (f32x4)(0.f);
    a0 = mfma16(ag0, *(const short8*)(gwp + ((size_t)(f0  )*64 + l)*8), a0);
    a0 = mfma16(ag1, *(const short8*)(gwp + ((size_t)(f0+1)*64 + l)*8), a0);
    a1 = mfma16(ag0, *(const short8*)(gwp + ((size_t)(f1  )*64 + l)*8), a1);
    a1 = mfma16(ag1, *(const short8*)(gwp + ((size_t)(f1+1)*64 + l)*8), a1);
    int c0 = (2*cc)*16 + l15, c1 = (2*cc+1)*16 + l15;
    #pragma unroll
    for (int j=0;j<4;j++){
      int row = w*16 + l4*4 + j;
      abuf[row*256 + (((c0>>3)^(row&7))<<3) + (c0&7)] = f2bs(a0[j]);
      abuf[row*256 + (((c1>>3)^(row&7))<<3) + (c1&7)] = f2bs(a1[j]);
    }
  }
  __syncthreads();
  {
    const short* srcb = pass ? vx : kx;
    #pragma unroll
    for (int i=0;i<8;i++){
      int gid = tid + i*256;
      int row = gid>>5, cg = gid&31;
      short8 sv = *(const short8*)(srcb + ((size_t)(b*2048 + n0 + row))*256 + cg*8);
      short* ap = &abuf[row*256 + ((cg^(row&7))<<3)];
      short8 av = *(const short8*)ap;
      short8 ov;
      #pragma unroll
      for (int e=0;e<8;e++) ov[e] = f2bs(bf2f(av[e]) + bf2f(sv[e]));
      *(short8*)ap = ov;
    }
  }
  __syncthreads();
  short8 af[8];
  #pragma unroll
  for (int kk=0;kk<8;kk++)
    af[kk] = *(const short8*)&abuf[ar*256 + (((kk*4+l4) ^ (ar&7))<<3)];

  if (pass == 0){
    float p0=0.f,p1=0.f,p2=0.f,p3=0.f;
    #pragma unroll 2
    for (int cc=0; cc<8; ++cc){
      int ct0 = 2*cc, ct1 = 2*cc+1;
      f32x4 a0 = (f32x4)(0.f), a1 = (f32x4)(0.f);
      #pragma unroll
      for (int kk=0;kk<8;kk++){
        a0 = mfma16(af[kk], *(const short8*)(f1wp + (((size_t)ct0*8 + kk)*64 + l)*8), a0);
        a1 = mfma16(af[kk], *(const short8*)(f1wp + (((size_t)ct1*8 + kk)*64 + l)*8), a1);
      }
      int c0 = ct0*16 + l15, c1 = ct1*16 + l15;
      float q0=sqf2[c0], b0=sf1b[c0], q1=sqf2[c1], b1=sf1b[c1];
      p0 += fmaxf(a0[0]+b0,0.f)*q0 + fmaxf(a1[0]+b1,0.f)*q1;
      p1 += fmaxf(a0[1]+b0,0.f)*q0 + fmaxf(a1[1]+b1,0.f)*q1;
      p2 += fmaxf(a0[2]+b0,0.f)*q0 + fmaxf(a1[2]+b1,0.f)*q1;
      p3 += fmaxf(a0[3]+b0,0.f)*q0 + fmaxf(a1[3]+b1,0.f)*q1;
    }
    #pragma unroll
    for (int o=8;o;o>>=1){
      p0 += __shfl_xor(p0,o); p1 += __shfl_xor(p1,o);
      p2 += __shfl_xor(p2,o); p3 += __shfl_xor(p3,o);
    }
    if (l15 == 0){
      float pj[4] = {p0,p1,p2,p3};
      #pragma unroll
      for (int j=0;j<4;j++){
        int row = w*16 + l4*4 + j;
        float dd = clampf((pj[j] + smisc[7]) * 0.0625f, -30.f, 30.f);
        dots[(size_t)bs*2048 + n0 + row] = dd;
      }
    }
  } else {
    #pragma unroll 2
    for (int cc=0; cc<8; ++cc){
      int ct0 = 2*cc, ct1 = 2*cc+1;
      f32x4 a0 = (f32x4)(0.f), a1 = (f32x4)(0.f);
      #pragma unroll
      for (int kk=0;kk<8;kk++){
        a0 = mfma16(af[kk], *(const short8*)(f1wp + (((size_t)ct0*8 + kk)*64 + l)*8), a0);
        a1 = mfma16(af[kk], *(const short8*)(f1wp + (((size_t)ct1*8 + kk)*64 + l)*8), a1);
      }
      int c0 = ct0*16 + l15, c1 = ct1*16 + l15;
      float b0=sf1b[c0], b1=sf1b[c1];
      #pragma unroll
      for (int j=0;j<4;j++){
        int row = w*16 + l4*4 + j;
        abuf[row*256 + (((c0>>3)^(row&7))<<3) + (c0&7)] = f2bs(fmaxf(a0[j]+b0,0.f));
        abuf[row*256 + (((c1>>3)^(row&7))<<3) + (c1&7)] = f2bs(fmaxf(a1[j]+b1,0.f));
      }
    }
    __syncthreads();
    #pragma unroll
    for (int i=0;i<8;i++){
      int gid = tid + i*256;
      int row = gid>>5, cg = gid&31;
      short8 av = *(const short8*)&abuf[row*256 + ((cg^(row&7))<<3)];
      *(short8*)(hv + ((size_t)(bs*2048 + n0 + row))*256 + cg*8) = av;
    }
  }
}

// ---------------- softmax (t=3 only) ----------------
__global__ __launch_bounds__(256) void k_softmax(const float* __restrict__ dots, float* __restrict__ aun,
                                                 float* __restrict__ sump){
  int blk = blockIdx.x;
  int b = blk >> 3, chunk = blk & 7;
  int n = chunk*256 + threadIdx.x;
  float d[8];
  #pragma unroll
  for (int s=0;s<8;s++) d[s] = dots[(size_t)(b*8+s)*2048 + n];
  float m = d[0];
  #pragma unroll
  for (int s=1;s<8;s++) m = fmaxf(m, d[s]);
  float e[8]; float sum = 0.f;
  #pragma unroll
  for (int s=0;s<8;s++){ e[s] = expf(d[s]-m); sum += e[s]; }
  float inv = 1.f/sum;
  __shared__ float red[4][8];
  int wv = threadIdx.x>>6, ln = threadIdx.x&63;
  #pragma unroll
  for (int s=0;s<8;s++){
    float a = e[s]*inv + 1e-8f;
    aun[(size_t)(b*8+s)*2048 + n] = a;
    float v = a;
    #pragma unroll
    for (int o=32;o;o>>=1) v += __shfl_xor(v,o);
    if (ln == 0) red[wv][s] = v;
  }
  __syncthreads();
  if (threadIdx.x < 8){
    int s = threadIdx.x;
    sump[(b*8+s)*8 + chunk] = red[0][s]+red[1][s]+red[2][s]+red[3][s];
  }
}

// ---------------- fused softmax + weighted partial reductions (t<3) ----------------
__global__ __launch_bounds__(256) void k_c1(const float* __restrict__ dots, const short* __restrict__ hv,
    const float* __restrict__ coords, float* __restrict__ hvpart, float* __restrict__ mompart,
    float* __restrict__ sump){
  int chunk = blockIdx.x, bs = blockIdx.y, b = bs >> 3, so = bs & 7;
  int t = threadIdx.x;
  int nb = chunk*256;
  __shared__ float wsm[256];
  __shared__ __align__(16) short tile[16*256];
  {
    float d[8];
    #pragma unroll
    for (int s=0;s<8;s++) d[s] = dots[(size_t)(b*8+s)*2048 + nb + t];
    float m = d[0];
    #pragma unroll
    for (int s=1;s<8;s++) m = fmaxf(m, d[s]);
    float sum = 0.f; float eo = 0.f;
    #pragma unroll
    for (int s=0;s<8;s++){ float e = expf(d[s]-m); sum += e; if (s==so) eo = e; }
    wsm[t] = eo/sum + 1e-8f;
  }
  __syncthreads();
  float acc = 0.f;
  const short* hbase = hv + ((size_t)bs*2048 + nb)*256;
  #pragma unroll 1
  for (int c16=0; c16<16; ++c16){
    #pragma unroll
    for (int rep=0; rep<2; ++rep){
      int idx = t + rep*256;
      int r = idx>>5, cg = idx&31;
      *(short8*)&tile[r*256 + cg*8] = *(const short8*)(hbase + (size_t)(c16*16+r)*256 + cg*8);
    }
    __syncthreads();
    #pragma unroll 4
    for (int n2=0;n2<16;n2++)
      acc += wsm[c16*16+n2]*bf2f(tile[n2*256+t]);
    __syncthreads();
  }
  hvpart[(size_t)(bs*8+chunk)*256 + t] = acc;
  float wv = wsm[t];
  const float* cp = coords + ((size_t)(b*2048) + nb + t)*3;
  float c0=cp[0], c1=cp[1], c2=cp[2];
  float mv[7] = {wv*c0, wv*c1, wv*c2, wv*c0*c0, wv*c1*c1, wv*c2*c2, wv};
  __shared__ float red[4][7];
  int wvx = t>>6, ln = t&63;
  #pragma unroll
  for (int i=0;i<7;i++){
    float v = mv[i];
    #pragma unroll
    for (int o=32;o;o>>=1) v += __shfl_xor(v,o);
    if (ln==0) red[wvx][i] = v;
  }
  __syncthreads();
  if (t<7){
    float r = red[0][t]+red[1][t]+red[2][t]+red[3][t];
    if (t<6) mompart[(bs*8+chunk)*6 + t] = r;
    else     sump[bs*8 + chunk] = r;
  }
}

// ---------------- final per-(b,s), 1024 threads: u, GRU, LN, MLP, qprep ----------------
__global__ __launch_bounds__(1024) void k_c2(
    const float* __restrict__ hvpart, const float* __restrict__ mompart, const float* __restrict__ sump,
    const float* __restrict__ f2w, const float* __restrict__ f2b,
    float* __restrict__ sp, float* __restrict__ ssb,
    const short* __restrict__ wihp, const short* __restrict__ whhp,
    const float* __restrict__ bih, const float* __restrict__ bhh,
    const float* __restrict__ m_ng, const float* __restrict__ m_nb,
    const short* __restrict__ m1wp, const float* __restrict__ m1b,
    const short* __restrict__ m2wp, const float* __restrict__ m2b,
    float* __restrict__ slots,
    const float* __restrict__ ng, const float* __restrict__ nbv, const float* __restrict__ Qw,
    const float* __restrict__ f2wT,
    float* __restrict__ qf2, float* __restrict__ qbv){
  int bs = blockIdx.x, t = threadIdx.x;
  int lo = t & 255, grp = t >> 8;
  __shared__ float hs[256], u[256], spv[256], hln[256], r1[1024];
  __shared__ float gis[768], ghs[768];
  __shared__ float red4[4][256];
  __shared__ float sc[8], rtmp[8];

  red4[grp][lo] = hvpart[(size_t)(bs*8+grp*2)*256+lo] + hvpart[(size_t)(bs*8+grp*2+1)*256+lo];
  if (t < 256) spv[lo] = slots[bs*256+lo];
  if (t == 0){
    float A0=0.f;
    for (int c=0;c<8;c++) A0 += sump[bs*8+c];
    sc[0]=A0; sc[1]=A0+1e-8f;
  }
  if (t >= 64 && t < 70){
    int i = t-64;
    float mm=0.f;
    for (int c=0;c<8;c++) mm += mompart[(bs*8+c)*6 + i];
    sc[2+i] = mm;
  }
  __syncthreads();
  if (t < 256) hs[lo] = red4[0][lo]+red4[1][lo]+red4[2][lo]+red4[3][lo];
  if (t < 3){
    float A0=sc[0], denom=sc[1];
    float A1 = sc[2+t], A2 = sc[5+t];
    float p = A1/denom;
    float var = (A2 - 2.f*p*A1 + p*p*A0)/denom + 1e-6f;
    sp[bs*3+t] = p; ssb[bs*3+t] = clampf(sqrtf(var),0.2f,5.f);
  }
  __syncthreads();
  // u partial (4-way K split over f2w rows)
  {
    const float4* fr = (const float4*)(f2w + (size_t)lo*256 + grp*64);
    const float* hsp = hs + grp*64;
    float dd = 0.f;
    #pragma unroll 4
    for (int i=0;i<16;i++){
      float4 w4 = fr[i];
      dd += hsp[i*4+0]*w4.x + hsp[i*4+1]*w4.y + hsp[i*4+2]*w4.z + hsp[i*4+3]*w4.w;
    }
    red4[grp][lo] = dd;
  }
  __syncthreads();
  if (t < 256)
    u[lo] = n2nf((red4[0][lo]+red4[1][lo]+red4[2][lo]+red4[3][lo] + sc[0]*f2b[lo])/sc[1]);
  __syncthreads();
  // GRU (768 outputs, bf16 weights)
  if (t < 768){
    const short8* wr = (const short8*)(wihp + (size_t)t*256);
    const short8* hr = (const short8*)(whhp + (size_t)t*256);
    float si = bih[t], sh = bhh[t];
    #pragma unroll 4
    for (int i=0;i<32;i++){
      short8 a = wr[i], b8 = hr[i];
      #pragma unroll
      for (int e=0;e<8;e++){
        si += u[i*8+e]*bf2f(a[e]);
        sh += spv[i*8+e]*bf2f(b8[e]);
      }
    }
    gis[t]=si; ghs[t]=sh;
  }
  __syncthreads();
  float hnewv = 0.f;
  if (t < 256){
    float rg = sigmoidf(gis[lo]+ghs[lo]);
    float zg = sigmoidf(gis[256+lo]+ghs[256+lo]);
    float nn = tanhf(gis[512+lo] + rg*ghs[512+lo]);
    hnewv = (1.f-zg)*nn + zg*spv[lo];
    red4[0][lo] = hnewv;
  }
  __syncthreads();
  if (t < 64){
    float s = red4[0][t]+red4[0][t+64]+red4[0][t+128]+red4[0][t+192];
    #pragma unroll
    for (int o=32;o;o>>=1) s += __shfl_xor(s,o);
    if (t==0) rtmp[0] = s*(1.f/256.f);
  }
  __syncthreads();
  if (t < 64){
    float m = rtmp[0], s=0.f;
    #pragma unroll
    for (int i=0;i<4;i++){ float d = red4[0][t+64*i]-m; s += d*d; }
    #pragma unroll
    for (int o=32;o;o>>=1) s += __shfl_xor(s,o);
    if (t==0) rtmp[1] = s*(1.f/256.f);
  }
  __syncthreads();
  if (t < 256)
    hln[lo] = (hnewv - rtmp[0])*(1.f/sqrtf(rtmp[1]+1e-5f))*m_ng[lo] + m_nb[lo];
  __syncthreads();
  // m1 (1024 outputs)
  {
    const short8* mr = (const short8*)(m1wp + (size_t)t*256);
    float s = m1b[t];
    #pragma unroll 4
    for (int i=0;i<32;i++){
      short8 a = mr[i];
      #pragma unroll
      for (int e=0;e<8;e++) s += hln[i*8+e]*bf2f(a[e]);
    }
    r1[t] = fmaxf(s, 0.f);
  }
  __syncthreads();
  // m2 (256 outputs, 4-way K split over K=1024)
  {
    const short8* mr = (const short8*)(m2wp + (size_t)lo*1024 + grp*256);
    const float* rp = r1 + grp*256;
    float s = 0.f;
    #pragma unroll 4
    for (int i=0;i<32;i++){
      short8 a = mr[i];
      #pragma unroll
      for (int e=0;e<8;e++) s += rp[i*8+e]*bf2f(a[e]);
    }
    red4[grp][lo] = s;
  }
  __syncthreads();
  float sl = 0.f;
  if (t < 256){
    sl = n2nf(hnewv + m2b[lo] + red4[0][lo]+red4[1][lo]+red4[2][lo]+red4[3][lo]);
    slots[bs*256+lo] = sl;
    red4[0][lo] = sl;
  }
  __syncthreads();
  // qprep: LN(sl)
  if (t < 64){
    float s = red4[0][t]+red4[0][t+64]+red4[0][t+128]+red4[0][t+192];
    #pragma unroll
    for (int o=32;o;o>>=1) s += __shfl_xor(s,o);
    if (t==0) rtmp[2] = s*(1.f/256.f);
  }
  __syncthreads();
  if (t < 64){
    float m = rtmp[2], s=0.f;
    #pragma unroll
    for (int i=0;i<4;i++){ float d = red4[0][t+64*i]-m; s += d*d; }
    #pragma unroll
    for (int o=32;o;o>>=1) s += __shfl_xor(s,o);
    if (t==0) rtmp[3] = s*(1.f/256.f);
  }
  __syncthreads();
  if (t < 256)
    hs[lo] = (sl - rtmp[2])*(1.f/sqrtf(rtmp[3]+1e-5f))*ng[lo] + nbv[lo];   // sn
  __syncthreads();
  // q partial (Qw fp32 rows, 4-way K split)
  {
    const float4* qr = (const float4*)(Qw + (size_t)lo*256 + grp*64);
    const float* snp = hs + grp*64;
    float s = 0.f;
    #pragma unroll 4
    for (int i=0;i<16;i++){
      float4 w4 = qr[i];
      s += snp[i*4+0]*w4.x + snp[i*4+1]*w4.y + snp[i*4+2]*w4.z + snp[i*4+3]*w4.w;
    }
    red4[grp][lo] = s;
  }
  __syncthreads();
  if (t < 256) u[lo] = red4[0][lo]+red4[1][lo]+red4[2][lo]+red4[3][lo];   // q
  __syncthreads();
  // qf2 partial (f2wT fp32 rows)
  {
    const float4* fr = (const float4*)(f2wT + (size_t)lo*256 + grp*64);
    const float* qp = u + grp*64;
    float s = 0.f;
    #pragma unroll 4
    for (int i=0;i<16;i++){
      float4 w4 = fr[i];
      s += qp[i*4+0]*w4.x + qp[i*4+1]*w4.y + qp[i*4+2]*w4.z + qp[i*4+3]*w4.w;
    }
    red4[grp][lo] = s;
  }
  __syncthreads();
  if (t < 256)
    qf2[bs*256+lo] = red4[0][lo]+red4[1][lo]+red4[2][lo]+red4[3][lo];
  if (t < 64){
    float s = u[t]*f2b[t] + u[t+64]*f2b[t+64] + u[t+128]*f2b[t+128] + u[t+192]*f2b[t+192];
    #pragma unroll
    for (int o=32;o;o>>=1) s += __shfl_xor(s,o);
    if (t==0) qbv[bs] = s;
  }
}

__global__ __launch_bounds__(256) void k_attn_out(const float* __restrict__ aun, const float* __restrict__ sump,
                                                  float* __restrict__ outp){
  int g = blockIdx.x*256 + threadIdx.x;
  int bs = g >> 11;
  __shared__ float dsh;
  if (threadIdx.x == 0){
    float s=0.f;
    for (int c=0;c<8;c++) s += sump[bs*8+c];
    dsh = s + 1e-8f;
  }
  __syncthreads();
  outp[g] = aun[g] / dsh;
}

__global__ __launch_bounds__(256) void k_final(const float* __restrict__ slots,
    const float* __restrict__ fw, const float* __restrict__ fb, float* __restrict__ outp){
  int bs = blockIdx.x, t = threadIdx.x;
  __shared__ float sl[256];
  sl[t] = slots[bs*256+t];
  __syncthreads();
  const float4* fr = (const float4*)(fw + (size_t)t*256);
  float s = fb[t];
  for (int d4=0; d4<64; ++d4){
    float4 w4 = fr[d4];
    s += sl[d4*4+0]*w4.x + sl[d4*4+1]*w4.y + sl[d4*4+2]*w4.z + sl[d4*4+3]*w4.w;
  }
  outp[bs*256+t] = s;
}

extern "C" void kernel_launch(void* const* d_in, const int* in_sizes, int n_in,
                              void* d_out, int out_size, void* d_ws, size_t ws_size,
                              hipStream_t stream){
  const float* p_inputs = (const float*)d_in[0];
  const float* p_coords = (const float*)d_in[1];
  const float* p_slotsp = (const float*)d_in[2];
  const float* p_Ss0 = (const float*)d_in[3];
  const float* p_Sp0 = (const float*)d_in[4];
  const float* p_Qw  = (const float*)d_in[5];
  const float* p_Kw  = (const float*)d_in[6];
  const float* p_Vw  = (const float*)d_in[7];
  const float* p_gw  = (const float*)d_in[8];
  const float* p_gb  = (const float*)d_in[9];
  const float* p_f1w = (const float*)d_in[10];
  const float* p_f1b = (const float*)d_in[11];
  const float* p_f2w = (const float*)d_in[12];
  const float* p_f2b = (const float*)d_in[13];
  const float* p_ng  = (const float*)d_in[14];
  const float* p_nb  = (const float*)d_in[15];
  const float* p_wih = (const float*)d_in[16];
  const float* p_whh = (const float*)d_in[17];
  const float* p_bih = (const float*)d_in[18];
  const float* p_bhh = (const float*)d_in[19];
  const float* p_mng = (const float*)d_in[20];
  const float* p_mnb = (const float*)d_in[21];
  const float* p_m1w = (const float*)d_in[22];
  const float* p_m1b = (const float*)d_in[23];
  const float* p_m2w = (const float*)d_in[24];
  const float* p_m2b = (const float*)d_in[25];
  const float* p_i0g = (const float*)d_in[26];
  const float* p_i0b = (const float*)d_in[27];
  const float* p_i1w = (const float*)d_in[28];
  const float* p_i1b = (const float*)d_in[29];
  const float* p_i2w = (const float*)d_in[30];
  const float* p_i2b = (const float*)d_in[31];
  const float* p_i3g = (const float*)d_in[32];
  const float* p_i3b = (const float*)d_in[33];
  const float* p_fw  = (const float*)d_in[34];
  const float* p_fb  = (const float*)d_in[35];

  char* ws = (char*)d_ws;
  size_t off = 0;
  auto alloc = [&](size_t bytes)->char*{
    char* p = ws + off;
    off = (off + bytes + 255) & ~(size_t)255;
    return p;
  };
  short* xln   = (short*)alloc(8192ull*768*2);
  short* h1    = (short*)alloc(8192ull*768*2);
  float* x2    = (float*)alloc(8192ull*256*4);
  short* xenc  = (short*)alloc(8192ull*256*2);
  short* kxb   = (short*)alloc(8192ull*256*2);
  short* vxb   = (short*)alloc(8192ull*256*2);
  short* hvb   = (short*)alloc(32ull*2048*256*2);
  float* dots  = (float*)alloc(32ull*2048*4);
  float* aun   = (float*)alloc(32ull*2048*4);
  float* sump  = (float*)alloc(32*8*4);
  float* hvpart= (float*)alloc(32ull*8*256*4);
  float* mompart=(float*)alloc(32*8*6*4);
  short* i1wp  = (short*)alloc(768ull*768*2);
  short* i2wp  = (short*)alloc(256ull*768*2);
  short* kwp   = (short*)alloc(256ull*256*2);
  short* vwp   = (short*)alloc(256ull*256*2);
  short* f1wp  = (short*)alloc(256ull*256*2);
  short* gwp   = (short*)alloc(256ull*64*2);
  short* wihp  = (short*)alloc(768ull*256*2);
  short* whhp  = (short*)alloc(768ull*256*2);
  short* m1wp  = (short*)alloc(1024ull*256*2);
  short* m2wp  = (short*)alloc(256ull*1024*2);
  float* f2wT  = (float*)alloc(256ull*256*4);
  float* slots = (float*)alloc(32*256*4);
  float* qf2   = (float*)alloc(32*256*4);
  float* qbv   = (float*)alloc(32*4);
  float* spb   = (float*)alloc(32*3*4);
  float* ssbuf = (float*)alloc(32*3*4);

  auto cvt = [&](const float* s, short* dst, int n){
    k_convert<<<(n+255)/256, 256, 0, stream>>>(s, dst, n);
  };
  k_pack_w<<<(768*768/8+255)/256,256,0,stream>>>(p_i1w, i1wp, 768, 768*768/8);
  k_pack_w<<<(256*768/8+255)/256,256,0,stream>>>(p_i2w, i2wp, 768, 256*768/8);
  k_pack_w<<<(256*256/8+255)/256,256,0,stream>>>(p_Kw,  kwp,  256, 256*256/8);
  k_pack_w<<<(256*256/8+255)/256,256,0,stream>>>(p_Vw,  vwp,  256, 256*256/8);
  k_pack_w<<<(256*256/8+255)/256,256,0,stream>>>(p_f1w, f1wp, 256, 256*256/8);
  k_pack_gw<<<8,256,0,stream>>>(p_gw, p_gb, gwp);
  cvt(p_wih, wihp, 768*256);
  cvt(p_whh, whhp, 768*256);
  cvt(p_m1w, m1wp, 1024*256);
  cvt(p_m2w, m2wp, 256*1024);
  k_transpose256<<<256,256,0,stream>>>(p_f2w, f2wT);
  k_init<<<32,256,0,stream>>>(p_slotsp, p_Sp0, p_Ss0, slots, spb, ssbuf,
                              p_ng, p_nb, p_Qw, f2wT, p_f2b, qf2, qbv);

  k_ln768<<<8192,256,0,stream>>>(p_inputs, p_i0g, p_i0b, xln);
  k_gemm<<<dim3(128,6),256,0,stream>>>(xln, i1wp, p_i1b, h1, 768, 768, 1|2|4);
  k_gemm<<<dim3(128,2),256,0,stream>>>(h1, i2wp, p_i2b, x2, 256, 768, 1);
  k_ln256<<<8192,256,0,stream>>>(x2, p_i3g, p_i3b, xenc);
  k_gemm<<<dim3(128,2),256,0,stream>>>(xenc, kwp, nullptr, kxb, 256, 256, 4);
  k_gemm<<<dim3(128,2),256,0,stream>>>(xenc, vwp, nullptr, vxb, 256, 256, 4);

  float* outf = (float*)d_out;
  for (int t=0;t<4;t++){
    k_isa_a<<<dim3(32,32,(t<3)?2:1),256,0,stream>>>(p_coords, spb, ssbuf, gwp, kxb, vxb, f1wp, p_f1b, qf2, qbv, dots, hvb);
    if (t < 3){
      k_c1<<<dim3(8,32),256,0,stream>>>(dots, hvb, p_coords, hvpart, mompart, sump);
      k_c2<<<32,1024,0,stream>>>(hvpart, mompart, sump, p_f2w, p_f2b, spb, ssbuf,
                                 wihp, whhp, p_bih, p_bhh, p_mng, p_mnb,
                                 m1wp, p_m1b, m2wp, p_m2b, slots,
                                 p_ng, p_nb, p_Qw, f2wT, qf2, qbv);
    } else {
      k_softmax<<<32,256,0,stream>>>(dots, aun, sump);
      k_attn_out<<<256,256,0,stream>>>(aun, sump, outf + 8192);
    }
  }
  k_final<<<32,256,0,stream>>>(slots, p_fw, p_fb, outf);
}